// Round 1
// baseline (150.580 us; speedup 1.0000x reference)
//
#include <hip/hip_runtime.h>
#include <math.h>

#define VN_EPS   1e-6f
#define NEG      0.2f
#define POS      0.8f   // 1 - NEG

__device__ __forceinline__ float group16_sum(float v) {
    v += __shfl_xor(v, 1);
    v += __shfl_xor(v, 2);
    v += __shfl_xor(v, 4);
    v += __shfl_xor(v, 8);
    return v;
}

// one block = 256 threads = 16 points; 16 lanes (one per neighbor k) per point.
__global__ __launch_bounds__(256) void areconv_kernel(
    const float* __restrict__ q_pts,    // [N,3]
    const float* __restrict__ s_pts,    // [N2,3]
    const int*   __restrict__ nbr,      // [N,16]
    const float* __restrict__ wb,       // [3,256]
    const float* __restrict__ w_vn,     // [3,16]
    const float* __restrict__ wd_vn,    // [3,16]
    const float* __restrict__ w_h1,     // [16,8]
    const float* __restrict__ w_h2,     // [8,8]
    const float* __restrict__ b_h2,     // [8]
    const float* __restrict__ wd_relu,  // [32,32]
    const float* __restrict__ w_un,     // [32,64]
    const float* __restrict__ wd_un,    // [32,64]
    float* __restrict__ out,            // [N,64,3]
    int N)
{
    const float BN_SCALE = 0.999994993f;  // float32(1/sqrt(1+1e-5))

    // per-point staging; stride 100 floats so the 4 groups of a wave land in
    // distinct LDS banks (p_slot*100 % 32 = p_slot*4).
    __shared__ float feats_s [16][100];   // [p_slot][h*3+d], h<32
    __shared__ float feats2_s[16][100];   // [p_slot][o*3+d], o<32

    const int tid    = threadIdx.x;
    const int p_slot = tid >> 4;      // 0..15 point within block
    const int k      = tid & 15;      // neighbor index
    const int n      = blockIdx.x * 16 + p_slot;
    if (n >= N) return;   // no barriers anywhere, early-return is safe

    // ---- gather + center + cross -> local frame L[c][d] -----------------
    const float qx = q_pts[n * 3 + 0];
    const float qy = q_pts[n * 3 + 1];
    const float qz = q_pts[n * 3 + 2];
    const int   id = nbr[n * 16 + k];
    const float px = s_pts[id * 3 + 0] - qx;
    const float py = s_pts[id * 3 + 1] - qy;
    const float pz = s_pts[id * 3 + 2] - qz;

    const float cx = group16_sum(px) * 0.0625f;
    const float cy = group16_sum(py) * 0.0625f;
    const float cz = group16_sum(pz) * 0.0625f;

    const float rx = py * cz - pz * cy;
    const float ry = pz * cx - px * cz;
    const float rz = px * cy - py * cx;

    float L[3][3] = {{px, py, pz}, {cx, cy, cz}, {rx, ry, rz}};

    // ---- score net: VNLinearLeakyReLU(3->16) -> ||.|| --------------------
    float sn[16];
#pragma unroll
    for (int o = 0; o < 16; ++o) {
        const float wv0 = w_vn[o],  wv1 = w_vn[16 + o],  wv2 = w_vn[32 + o];
        const float wd0 = wd_vn[o], wd1 = wd_vn[16 + o], wd2 = wd_vn[32 + o];
        float pv[3], dv[3];
        float dot = 0.f, dsq = 0.f;
#pragma unroll
        for (int d = 0; d < 3; ++d) {
            const float pp = BN_SCALE * (L[0][d] * wv0 + L[1][d] * wv1 + L[2][d] * wv2);
            const float dd = L[0][d] * wd0 + L[1][d] * wd1 + L[2][d] * wd2;
            pv[d] = pp; dv[d] = dd;
            dot += pp * dd;
            dsq += dd * dd;
        }
        const float f = dot / (dsq + VN_EPS);
        float acc = 0.f;
#pragma unroll
        for (int d = 0; d < 3; ++d) {
            const float corr = pv[d] - f * dv[d];
            const float sel  = (dot >= 0.f) ? pv[d] : corr;
            const float a    = NEG * pv[d] + POS * sel;
            acc += a * a;
        }
        sn[o] = sqrtf(acc);
    }

    // ---- 16->8 conv + BN + relu ------------------------------------------
    float tt[8];
#pragma unroll
    for (int o = 0; o < 8; ++o) {
        float t = 0.f;
#pragma unroll
        for (int c = 0; c < 16; ++c) t += sn[c] * w_h1[c * 8 + o];
        tt[o] = fmaxf(t * BN_SCALE, 0.f);
    }

    // ---- 8->8 conv + bias, softmax over the 8 channels -------------------
    float sc[8];
    float mx = -1e30f;
#pragma unroll
    for (int o = 0; o < 8; ++o) {
        float u = b_h2[o];
#pragma unroll
        for (int c = 0; c < 8; ++c) u += tt[c] * w_h2[c * 8 + o];
        sc[o] = u;
        mx = fmaxf(mx, u);
    }
    float se = 0.f;
#pragma unroll
    for (int o = 0; o < 8; ++o) { sc[o] = expf(sc[o] - mx); se += sc[o]; }
    const float inv_se = 1.f / se;
#pragma unroll
    for (int o = 0; o < 8; ++o) sc[o] *= inv_se;

    // ---- kernel-point correlation: per h, fold scores into wb, project,
    //      normalize, mean over k -> feats_s[p_slot][h][d] ------------------
#pragma unroll 4
    for (int h = 0; h < 32; ++h) {
        float w0 = 0.f, w1 = 0.f, w2 = 0.f;
#pragma unroll
        for (int s = 0; s < 8; ++s) {
            const float sv = sc[s];
            w0 += sv * wb[0 * 256 + s * 32 + h];
            w1 += sv * wb[1 * 256 + s * 32 + h];
            w2 += sv * wb[2 * 256 + s * 32 + h];
        }
        float v[3];
#pragma unroll
        for (int d = 0; d < 3; ++d)
            v[d] = L[0][d] * w0 + L[1][d] * w1 + L[2][d] * w2;
        const float nr   = sqrtf(v[0] * v[0] + v[1] * v[1] + v[2] * v[2]);
        const float innr = 1.f / fmaxf(nr, 1e-12f);
#pragma unroll
        for (int d = 0; d < 3; ++d) {
            float x = group16_sum(v[d] * innr);
            if (k == 0) feats_s[p_slot][h * 3 + d] = x * 0.0625f;
        }
    }
    // intra-wave LDS write->read; compiler orders via lgkmcnt, no barrier.

    // ---- VNLeakyReLU(32->32), distributed: lane k does o = k, k+16 -------
#pragma unroll
    for (int rep = 0; rep < 2; ++rep) {
        const int o = k + rep * 16;
        float d0 = 0.f, d1 = 0.f, d2 = 0.f;
#pragma unroll 8
        for (int h = 0; h < 32; ++h) {
            const float w = wd_relu[h * 32 + o];
            d0 += feats_s[p_slot][h * 3 + 0] * w;
            d1 += feats_s[p_slot][h * 3 + 1] * w;
            d2 += feats_s[p_slot][h * 3 + 2] * w;
        }
        const float p0 = feats_s[p_slot][o * 3 + 0];
        const float p1 = feats_s[p_slot][o * 3 + 1];
        const float p2 = feats_s[p_slot][o * 3 + 2];
        const float dot = p0 * d0 + p1 * d1 + p2 * d2;
        const float dsq = d0 * d0 + d1 * d1 + d2 * d2;
        const float f   = dot / (dsq + VN_EPS);
        const bool  pos = (dot >= 0.f);
        feats2_s[p_slot][o * 3 + 0] = NEG * p0 + POS * (pos ? p0 : (p0 - f * d0));
        feats2_s[p_slot][o * 3 + 1] = NEG * p1 + POS * (pos ? p1 : (p1 - f * d1));
        feats2_s[p_slot][o * 3 + 2] = NEG * p2 + POS * (pos ? p2 : (p2 - f * d2));
    }

    // ---- VNLinearLeakyReLU(32->64): lane k does o = k, k+16, k+32, k+48 --
#pragma unroll
    for (int rep = 0; rep < 4; ++rep) {
        const int o = k + rep * 16;
        float u0 = 0.f, u1 = 0.f, u2 = 0.f;
        float v0 = 0.f, v1 = 0.f, v2 = 0.f;
#pragma unroll 8
        for (int h = 0; h < 32; ++h) {
            const float a0 = feats2_s[p_slot][h * 3 + 0];
            const float a1 = feats2_s[p_slot][h * 3 + 1];
            const float a2 = feats2_s[p_slot][h * 3 + 2];
            const float wu = w_un[h * 64 + o];
            const float wd = wd_un[h * 64 + o];
            u0 += a0 * wu; u1 += a1 * wu; u2 += a2 * wu;
            v0 += a0 * wd; v1 += a1 * wd; v2 += a2 * wd;
        }
        u0 *= BN_SCALE; u1 *= BN_SCALE; u2 *= BN_SCALE;
        const float dot = u0 * v0 + u1 * v1 + u2 * v2;
        const float dsq = v0 * v0 + v1 * v1 + v2 * v2;
        const float f   = dot / (dsq + VN_EPS);
        const bool  pos = (dot >= 0.f);
        const long  base = (long)n * 192 + o * 3;
        out[base + 0] = NEG * u0 + POS * (pos ? u0 : (u0 - f * v0));
        out[base + 1] = NEG * u1 + POS * (pos ? u1 : (u1 - f * v1));
        out[base + 2] = NEG * u2 + POS * (pos ? u2 : (u2 - f * v2));
    }
}

extern "C" void kernel_launch(void* const* d_in, const int* in_sizes, int n_in,
                              void* d_out, int out_size, void* d_ws, size_t ws_size,
                              hipStream_t stream) {
    const float* q_pts   = (const float*)d_in[0];
    const float* s_pts   = (const float*)d_in[1];
    // d_in[2] = s_feats: unused by the reference
    const int*   nbr     = (const int*)  d_in[3];
    const float* wb      = (const float*)d_in[4];
    const float* w_vn    = (const float*)d_in[5];
    const float* wd_vn   = (const float*)d_in[6];
    const float* w_h1    = (const float*)d_in[7];
    const float* w_h2    = (const float*)d_in[8];
    const float* b_h2    = (const float*)d_in[9];
    const float* wd_relu = (const float*)d_in[10];
    const float* w_un    = (const float*)d_in[11];
    const float* wd_un   = (const float*)d_in[12];
    float* out = (float*)d_out;

    const int N = in_sizes[0] / 3;          // q_pts is [N,3]
    const int blocks = (N + 15) / 16;       // 16 points per block
    areconv_kernel<<<blocks, 256, 0, stream>>>(
        q_pts, s_pts, nbr, wb, w_vn, wd_vn, w_h1, w_h2, b_h2,
        wd_relu, w_un, wd_un, out, N);
}

// Round 2
// 129.102 us; speedup vs baseline: 1.1664x; 1.1664x over previous
//
#include <hip/hip_runtime.h>
#include <math.h>

#define VN_EPS   1e-6f
#define NEG      0.2f
#define POS      0.8f   // 1 - NEG

__device__ __forceinline__ float g16sum(float v) {
    // butterfly over the 16-lane subgroup (lanes differ in bits 0..3)
    v += __shfl_xor(v, 1);
    v += __shfl_xor(v, 2);
    v += __shfl_xor(v, 4);
    v += __shfl_xor(v, 8);
    return v;
}

// one wave = one point. lane = g*16 + k: k = neighbor (0..15), g = quarter (0..3).
// block = 256 threads = 4 waves = 4 points.
__global__ __launch_bounds__(256) void areconv_kernel(
    const float* __restrict__ q_pts,    // [N,3]
    const float* __restrict__ s_pts,    // [N2,3]
    const int*   __restrict__ nbr,      // [N,16]
    const float* __restrict__ wb,       // [3,256]
    const float* __restrict__ w_vn,     // [3,16]
    const float* __restrict__ wd_vn,    // [3,16]
    const float* __restrict__ w_h1,     // [16,8]
    const float* __restrict__ w_h2,     // [8,8]
    const float* __restrict__ b_h2,     // [8]
    const float* __restrict__ wd_relu,  // [32,32]
    const float* __restrict__ w_un,     // [32,64]
    const float* __restrict__ wd_un,    // [32,64]
    float* __restrict__ out,            // [N,64,3]
    int N)
{
    const float BN_SCALE = 0.999994993f;  // float32(1/sqrt(1+1e-5))

    // per-point LDS staging; stride 104 (multiple of 4 for b128 alignment).
    // all intra-wave producer->consumer: no __syncthreads needed (in-order DS).
    __shared__ float feats [4][104];   // [wave][h*3+d], h<32
    __shared__ float feats2[4][104];   // [wave][o*3+d], o<32

    const int tid  = threadIdx.x;
    const int wv   = tid >> 6;        // wave index in block = point slot
    const int lane = tid & 63;
    const int g    = (tid >> 4) & 3;  // quarter group 0..3
    const int k    = tid & 15;        // neighbor index
    const int n    = blockIdx.x * 4 + wv;
    if (n >= N) return;               // wave-uniform exit, no barriers anywhere

    // ---- gather + center + cross -> local frame L[c][d] ------------------
    const float qx = q_pts[n * 3 + 0];
    const float qy = q_pts[n * 3 + 1];
    const float qz = q_pts[n * 3 + 2];
    const int   id = nbr[n * 16 + k];
    const float px = s_pts[id * 3 + 0] - qx;
    const float py = s_pts[id * 3 + 1] - qy;
    const float pz = s_pts[id * 3 + 2] - qz;

    const float cx = g16sum(px) * 0.0625f;
    const float cy = g16sum(py) * 0.0625f;
    const float cz = g16sum(pz) * 0.0625f;

    const float rx = py * cz - pz * cy;
    const float ry = pz * cx - px * cz;
    const float rz = px * cy - py * cx;

    const float L[3][3] = {{px, py, pz}, {cx, cy, cz}, {rx, ry, rz}};

    // ---- score net part 1: VNLinearLeakyReLU(3->16) -> ||.||, distributed:
    //      lane (g,k) computes channels o = 4g..4g+3 ------------------------
    float sn_loc[4];
#pragma unroll
    for (int j = 0; j < 4; ++j) {
        const int o = g * 4 + j;
        const float wv0 = w_vn[o],  wv1 = w_vn[16 + o],  wv2 = w_vn[32 + o];
        const float wd0 = wd_vn[o], wd1 = wd_vn[16 + o], wd2 = wd_vn[32 + o];
        float pv[3], dv[3];
        float dot = 0.f, dsq = 0.f;
#pragma unroll
        for (int d = 0; d < 3; ++d) {
            const float pp = BN_SCALE * (L[0][d] * wv0 + L[1][d] * wv1 + L[2][d] * wv2);
            const float dd = L[0][d] * wd0 + L[1][d] * wd1 + L[2][d] * wd2;
            pv[d] = pp; dv[d] = dd;
            dot += pp * dd;
            dsq += dd * dd;
        }
        const float f = dot * __builtin_amdgcn_rcpf(dsq + VN_EPS);
        float acc = 0.f;
#pragma unroll
        for (int d = 0; d < 3; ++d) {
            const float corr = pv[d] - f * dv[d];
            const float sel  = (dot >= 0.f) ? pv[d] : corr;
            const float a    = NEG * pv[d] + POS * sel;
            acc += a * a;
        }
        sn_loc[j] = __builtin_amdgcn_sqrtf(acc);
    }

    // ---- 16->8 conv: partial over this lane's 4 channels, reduce across g
    //      (xor 16/32 flip g bits, keep k) ---------------------------------
    float tt[8];
#pragma unroll
    for (int o = 0; o < 8; ++o) {
        float t = sn_loc[0] * w_h1[(g * 4 + 0) * 8 + o]
                + sn_loc[1] * w_h1[(g * 4 + 1) * 8 + o]
                + sn_loc[2] * w_h1[(g * 4 + 2) * 8 + o]
                + sn_loc[3] * w_h1[(g * 4 + 3) * 8 + o];
        t += __shfl_xor(t, 16);
        t += __shfl_xor(t, 32);
        tt[o] = fmaxf(t * BN_SCALE, 0.f);
    }

    // ---- 8->8 conv + bias, softmax over channels -------------------------
    float sc[8];
    float mx = -1e30f;
#pragma unroll
    for (int o = 0; o < 8; ++o) {
        float u = b_h2[o];
#pragma unroll
        for (int c = 0; c < 8; ++c) u += tt[c] * w_h2[c * 8 + o];
        sc[o] = u;
        mx = fmaxf(mx, u);
    }
    float se = 0.f;
#pragma unroll
    for (int o = 0; o < 8; ++o) { sc[o] = __expf(sc[o] - mx); se += sc[o]; }
    const float inv_se = __builtin_amdgcn_rcpf(se);
#pragma unroll
    for (int o = 0; o < 8; ++o) sc[o] *= inv_se;

    // ---- kernel-point correlation: lane (g,k) handles h = 8g..8g+7.
    //      fold scores into wb, project, normalize, mean over k ------------
#pragma unroll
    for (int i = 0; i < 8; ++i) {
        const int h = g * 8 + i;
        float w0 = 0.f, w1 = 0.f, w2 = 0.f;
#pragma unroll
        for (int s = 0; s < 8; ++s) {
            const float sv = sc[s];
            w0 += sv * wb[0 * 256 + s * 32 + h];
            w1 += sv * wb[1 * 256 + s * 32 + h];
            w2 += sv * wb[2 * 256 + s * 32 + h];
        }
        const float v0 = L[0][0] * w0 + L[1][0] * w1 + L[2][0] * w2;
        const float v1 = L[0][1] * w0 + L[1][1] * w1 + L[2][1] * w2;
        const float v2 = L[0][2] * w0 + L[1][2] * w1 + L[2][2] * w2;
        const float vv   = v0 * v0 + v1 * v1 + v2 * v2;
        const float innr = __builtin_amdgcn_rsqf(fmaxf(vv, 1e-24f)); // 1/max(||v||,1e-12)
        const float x0 = g16sum(v0 * innr);
        const float x1 = g16sum(v1 * innr);
        const float x2 = g16sum(v2 * innr);
        if (k == 0) {
            feats[wv][h * 3 + 0] = x0 * 0.0625f;
            feats[wv][h * 3 + 1] = x1 * 0.0625f;
            feats[wv][h * 3 + 2] = x2 * 0.0625f;
        }
    }

    // ---- VNLeakyReLU(32->32): o = lane/2, h-range split by lane parity ----
    {
        const int o    = lane >> 1;
        const int half = lane & 1;
        float d0 = 0.f, d1 = 0.f, d2 = 0.f;
#pragma unroll 8
        for (int i = 0; i < 16; ++i) {
            const int h = half * 16 + i;
            const float w = wd_relu[h * 32 + o];
            d0 += feats[wv][h * 3 + 0] * w;
            d1 += feats[wv][h * 3 + 1] * w;
            d2 += feats[wv][h * 3 + 2] * w;
        }
        d0 += __shfl_xor(d0, 1);
        d1 += __shfl_xor(d1, 1);
        d2 += __shfl_xor(d2, 1);
        const float p0 = feats[wv][o * 3 + 0];
        const float p1 = feats[wv][o * 3 + 1];
        const float p2 = feats[wv][o * 3 + 2];
        const float dot = p0 * d0 + p1 * d1 + p2 * d2;
        const float dsq = d0 * d0 + d1 * d1 + d2 * d2;
        const float f   = dot * __builtin_amdgcn_rcpf(dsq + VN_EPS);
        const bool  pos = (dot >= 0.f);
        if (half == 0) {
            feats2[wv][o * 3 + 0] = NEG * p0 + POS * (pos ? p0 : (p0 - f * d0));
            feats2[wv][o * 3 + 1] = NEG * p1 + POS * (pos ? p1 : (p1 - f * d1));
            feats2[wv][o * 3 + 2] = NEG * p2 + POS * (pos ? p2 : (p2 - f * d2));
        }
    }

    // ---- VNLinearLeakyReLU(32->64): o = lane ------------------------------
    {
        const int o = lane;
        float u0 = 0.f, u1 = 0.f, u2 = 0.f;
        float v0 = 0.f, v1 = 0.f, v2 = 0.f;
#pragma unroll 8
        for (int h = 0; h < 32; ++h) {
            const float a0 = feats2[wv][h * 3 + 0];
            const float a1 = feats2[wv][h * 3 + 1];
            const float a2 = feats2[wv][h * 3 + 2];
            const float wu = w_un[h * 64 + o];
            const float wd = wd_un[h * 64 + o];
            u0 += a0 * wu; u1 += a1 * wu; u2 += a2 * wu;
            v0 += a0 * wd; v1 += a1 * wd; v2 += a2 * wd;
        }
        u0 *= BN_SCALE; u1 *= BN_SCALE; u2 *= BN_SCALE;
        const float dot = u0 * v0 + u1 * v1 + u2 * v2;
        const float dsq = v0 * v0 + v1 * v1 + v2 * v2;
        const float f   = dot * __builtin_amdgcn_rcpf(dsq + VN_EPS);
        const bool  pos = (dot >= 0.f);
        const long  base = (long)n * 192 + o * 3;
        out[base + 0] = NEG * u0 + POS * (pos ? u0 : (u0 - f * v0));
        out[base + 1] = NEG * u1 + POS * (pos ? u1 : (u1 - f * v1));
        out[base + 2] = NEG * u2 + POS * (pos ? u2 : (u2 - f * v2));
    }
}

extern "C" void kernel_launch(void* const* d_in, const int* in_sizes, int n_in,
                              void* d_out, int out_size, void* d_ws, size_t ws_size,
                              hipStream_t stream) {
    const float* q_pts   = (const float*)d_in[0];
    const float* s_pts   = (const float*)d_in[1];
    // d_in[2] = s_feats: unused by the reference
    const int*   nbr     = (const int*)  d_in[3];
    const float* wb      = (const float*)d_in[4];
    const float* w_vn    = (const float*)d_in[5];
    const float* wd_vn   = (const float*)d_in[6];
    const float* w_h1    = (const float*)d_in[7];
    const float* w_h2    = (const float*)d_in[8];
    const float* b_h2    = (const float*)d_in[9];
    const float* wd_relu = (const float*)d_in[10];
    const float* w_un    = (const float*)d_in[11];
    const float* wd_un   = (const float*)d_in[12];
    float* out = (float*)d_out;

    const int N = in_sizes[0] / 3;          // q_pts is [N,3]
    const int blocks = (N + 3) / 4;         // 1 wave per point, 4 points/block
    areconv_kernel<<<blocks, 256, 0, stream>>>(
        q_pts, s_pts, nbr, wb, w_vn, wd_vn, w_h1, w_h2, b_h2,
        wd_relu, w_un, wd_un, out, N);
}

// Round 3
// 128.560 us; speedup vs baseline: 1.1713x; 1.0042x over previous
//
#include <hip/hip_runtime.h>
#include <math.h>

#define VN_EPS   1e-6f
#define NEG      0.2f
#define POS      0.8f   // 1 - NEG

// ---- DPP 16-lane (row) reductions: VALU-only, no LDS pipe ----------------
// dpp_ctrl: row_shr:n = 0x110|n, row_ror:n = 0x120|n. bound_ctrl=true -> 0
// for invalid source lanes. All waves here are full (N divisible layouts),
// so exec-mask holes are not a concern.
template <int CTRL>
__device__ __forceinline__ float dpp_add(float v) {
    int s = __builtin_amdgcn_update_dpp(0, __float_as_int(v), CTRL, 0xf, 0xf, true);
    return v + __int_as_float(s);
}

// all 16 lanes of the row end with the row sum (rotate butterfly)
__device__ __forceinline__ float row16_allsum(float v) {
    v = dpp_add<0x128>(v);  // row_ror:8
    v = dpp_add<0x124>(v);  // row_ror:4
    v = dpp_add<0x122>(v);  // row_ror:2
    v = dpp_add<0x121>(v);  // row_ror:1
    return v;
}

// row sum accumulates into lane 15 of the row (shift tree)
__device__ __forceinline__ float row16_sum15(float v) {
    v = dpp_add<0x118>(v);  // row_shr:8
    v = dpp_add<0x114>(v);  // row_shr:4
    v = dpp_add<0x112>(v);  // row_shr:2
    v = dpp_add<0x111>(v);  // row_shr:1
    return v;
}

// one wave = one point. lane = g*16 + k: k = neighbor (0..15), g = quarter (0..3).
// block = 256 threads = 4 waves = 4 points.
__global__ __launch_bounds__(256) void areconv_kernel(
    const float* __restrict__ q_pts,    // [N,3]
    const float* __restrict__ s_pts,    // [N2,3]
    const int*   __restrict__ nbr,      // [N,16]
    const float* __restrict__ wb,       // [3,256]
    const float* __restrict__ w_vn,     // [3,16]
    const float* __restrict__ wd_vn,    // [3,16]
    const float* __restrict__ w_h1,     // [16,8]
    const float* __restrict__ w_h2,     // [8,8]
    const float* __restrict__ b_h2,     // [8]
    const float* __restrict__ wd_relu,  // [32,32]
    const float* __restrict__ w_un,     // [32,64]
    const float* __restrict__ wd_un,    // [32,64]
    float* __restrict__ out,            // [N,64,3]
    int N)
{
    const float BN_SCALE = 0.999994993f;  // float32(1/sqrt(1+1e-5))

    // per-point LDS staging; all producer->consumer intra-wave (in-order DS
    // pipe orders it; no __syncthreads anywhere).
    __shared__ float feats [4][104];   // [wave][h*3+d], h<32
    __shared__ float feats2[4][104];   // [wave][o*3+d], o<32

    const int tid  = threadIdx.x;
    const int wv   = tid >> 6;        // wave index in block = point slot
    const int lane = tid & 63;
    const int g    = (tid >> 4) & 3;  // quarter group 0..3
    const int k    = tid & 15;        // neighbor index
    const int n    = blockIdx.x * 4 + wv;
    if (n >= N) return;               // wave-uniform exit

    // ---- gather + center + cross -> local frame L[c][d] ------------------
    const float qx = q_pts[n * 3 + 0];
    const float qy = q_pts[n * 3 + 1];
    const float qz = q_pts[n * 3 + 2];
    const int   id = nbr[n * 16 + k];
    const float px = s_pts[id * 3 + 0] - qx;
    const float py = s_pts[id * 3 + 1] - qy;
    const float pz = s_pts[id * 3 + 2] - qz;

    const float cx = row16_allsum(px) * 0.0625f;
    const float cy = row16_allsum(py) * 0.0625f;
    const float cz = row16_allsum(pz) * 0.0625f;

    const float rx = py * cz - pz * cy;
    const float ry = pz * cx - px * cz;
    const float rz = px * cy - py * cx;

    const float L[3][3] = {{px, py, pz}, {cx, cy, cz}, {rx, ry, rz}};

    // ---- score net: VNLinearLeakyReLU(3->16) -> ||.||, lane (g,k) does
    //      channels o = 4g..4g+3 -------------------------------------------
    float sn_loc[4];
#pragma unroll
    for (int j = 0; j < 4; ++j) {
        const int o = g * 4 + j;
        const float wv0 = w_vn[o],  wv1 = w_vn[16 + o],  wv2 = w_vn[32 + o];
        const float wd0 = wd_vn[o], wd1 = wd_vn[16 + o], wd2 = wd_vn[32 + o];
        float pv[3], dv[3];
        float dot = 0.f, dsq = 0.f;
#pragma unroll
        for (int d = 0; d < 3; ++d) {
            const float pp = BN_SCALE * (L[0][d] * wv0 + L[1][d] * wv1 + L[2][d] * wv2);
            const float dd = L[0][d] * wd0 + L[1][d] * wd1 + L[2][d] * wd2;
            pv[d] = pp; dv[d] = dd;
            dot += pp * dd;
            dsq += dd * dd;
        }
        const float f = dot * __builtin_amdgcn_rcpf(dsq + VN_EPS);
        float acc = 0.f;
#pragma unroll
        for (int d = 0; d < 3; ++d) {
            const float corr = pv[d] - f * dv[d];
            const float sel  = (dot >= 0.f) ? pv[d] : corr;
            const float a    = NEG * pv[d] + POS * sel;
            acc += a * a;
        }
        sn_loc[j] = __builtin_amdgcn_sqrtf(acc);
    }

    // ---- 16->8 conv: partials over this lane's 4 channels, reduce across
    //      the 4 rows (xor 16/32 keep k, flip g) — cross-row, stays shfl ----
    float tt[8];
#pragma unroll
    for (int o = 0; o < 8; ++o) {
        float t = sn_loc[0] * w_h1[(g * 4 + 0) * 8 + o]
                + sn_loc[1] * w_h1[(g * 4 + 1) * 8 + o]
                + sn_loc[2] * w_h1[(g * 4 + 2) * 8 + o]
                + sn_loc[3] * w_h1[(g * 4 + 3) * 8 + o];
        t += __shfl_xor(t, 16);
        t += __shfl_xor(t, 32);
        tt[o] = fmaxf(t * BN_SCALE, 0.f);
    }

    // ---- 8->8 conv + bias, softmax over channels -------------------------
    float sc[8];
    float mx = -1e30f;
#pragma unroll
    for (int o = 0; o < 8; ++o) {
        float u = b_h2[o];
#pragma unroll
        for (int c = 0; c < 8; ++c) u += tt[c] * w_h2[c * 8 + o];
        sc[o] = u;
        mx = fmaxf(mx, u);
    }
    float se = 0.f;
#pragma unroll
    for (int o = 0; o < 8; ++o) { sc[o] = __expf(sc[o] - mx); se += sc[o]; }
    const float inv_se = __builtin_amdgcn_rcpf(se);
#pragma unroll
    for (int o = 0; o < 8; ++o) sc[o] *= inv_se;

    // ---- kernel-point correlation: lane (g,k) handles h = 8g..8g+7.
    //      fold scores into wb, project, normalize, mean over k (DPP tree,
    //      sum lands in k=15 which writes LDS) -----------------------------
#pragma unroll
    for (int i = 0; i < 8; ++i) {
        const int h = g * 8 + i;
        float w0 = 0.f, w1 = 0.f, w2 = 0.f;
#pragma unroll
        for (int s = 0; s < 8; ++s) {
            const float sv = sc[s];
            w0 += sv * wb[0 * 256 + s * 32 + h];
            w1 += sv * wb[1 * 256 + s * 32 + h];
            w2 += sv * wb[2 * 256 + s * 32 + h];
        }
        const float v0 = L[0][0] * w0 + L[1][0] * w1 + L[2][0] * w2;
        const float v1 = L[0][1] * w0 + L[1][1] * w1 + L[2][1] * w2;
        const float v2 = L[0][2] * w0 + L[1][2] * w1 + L[2][2] * w2;
        const float vv   = v0 * v0 + v1 * v1 + v2 * v2;
        const float innr = __builtin_amdgcn_rsqf(fmaxf(vv, 1e-24f)); // 1/max(||v||,1e-12)
        const float x0 = row16_sum15(v0 * innr);
        const float x1 = row16_sum15(v1 * innr);
        const float x2 = row16_sum15(v2 * innr);
        if (k == 15) {
            feats[wv][h * 3 + 0] = x0 * 0.0625f;
            feats[wv][h * 3 + 1] = x1 * 0.0625f;
            feats[wv][h * 3 + 2] = x2 * 0.0625f;
        }
    }

    // ---- VNLeakyReLU(32->32): o = lane/2, h-range split by lane parity ----
    {
        const int o    = lane >> 1;
        const int half = lane & 1;
        float d0 = 0.f, d1 = 0.f, d2 = 0.f;
#pragma unroll 8
        for (int i = 0; i < 16; ++i) {
            const int h = half * 16 + i;
            const float w = wd_relu[h * 32 + o];
            d0 += feats[wv][h * 3 + 0] * w;
            d1 += feats[wv][h * 3 + 1] * w;
            d2 += feats[wv][h * 3 + 2] * w;
        }
        d0 += __shfl_xor(d0, 1);
        d1 += __shfl_xor(d1, 1);
        d2 += __shfl_xor(d2, 1);
        const float p0 = feats[wv][o * 3 + 0];
        const float p1 = feats[wv][o * 3 + 1];
        const float p2 = feats[wv][o * 3 + 2];
        const float dot = p0 * d0 + p1 * d1 + p2 * d2;
        const float dsq = d0 * d0 + d1 * d1 + d2 * d2;
        const float f   = dot * __builtin_amdgcn_rcpf(dsq + VN_EPS);
        const bool  pos = (dot >= 0.f);
        if (half == 0) {
            feats2[wv][o * 3 + 0] = NEG * p0 + POS * (pos ? p0 : (p0 - f * d0));
            feats2[wv][o * 3 + 1] = NEG * p1 + POS * (pos ? p1 : (p1 - f * d1));
            feats2[wv][o * 3 + 2] = NEG * p2 + POS * (pos ? p2 : (p2 - f * d2));
        }
    }

    // ---- VNLinearLeakyReLU(32->64): o = lane ------------------------------
    {
        const int o = lane;
        float u0 = 0.f, u1 = 0.f, u2 = 0.f;
        float v0 = 0.f, v1 = 0.f, v2 = 0.f;
#pragma unroll 8
        for (int h = 0; h < 32; ++h) {
            const float a0 = feats2[wv][h * 3 + 0];
            const float a1 = feats2[wv][h * 3 + 1];
            const float a2 = feats2[wv][h * 3 + 2];
            const float wu = w_un[h * 64 + o];
            const float wd = wd_un[h * 64 + o];
            u0 += a0 * wu; u1 += a1 * wu; u2 += a2 * wu;
            v0 += a0 * wd; v1 += a1 * wd; v2 += a2 * wd;
        }
        u0 *= BN_SCALE; u1 *= BN_SCALE; u2 *= BN_SCALE;
        const float dot = u0 * v0 + u1 * v1 + u2 * v2;
        const float dsq = v0 * v0 + v1 * v1 + v2 * v2;
        const float f   = dot * __builtin_amdgcn_rcpf(dsq + VN_EPS);
        const bool  pos = (dot >= 0.f);
        const long  base = (long)n * 192 + o * 3;
        out[base + 0] = NEG * u0 + POS * (pos ? u0 : (u0 - f * v0));
        out[base + 1] = NEG * u1 + POS * (pos ? u1 : (u1 - f * v1));
        out[base + 2] = NEG * u2 + POS * (pos ? u2 : (u2 - f * v2));
    }
}

extern "C" void kernel_launch(void* const* d_in, const int* in_sizes, int n_in,
                              void* d_out, int out_size, void* d_ws, size_t ws_size,
                              hipStream_t stream) {
    const float* q_pts   = (const float*)d_in[0];
    const float* s_pts   = (const float*)d_in[1];
    // d_in[2] = s_feats: unused by the reference
    const int*   nbr     = (const int*)  d_in[3];
    const float* wb      = (const float*)d_in[4];
    const float* w_vn    = (const float*)d_in[5];
    const float* wd_vn   = (const float*)d_in[6];
    const float* w_h1    = (const float*)d_in[7];
    const float* w_h2    = (const float*)d_in[8];
    const float* b_h2    = (const float*)d_in[9];
    const float* wd_relu = (const float*)d_in[10];
    const float* w_un    = (const float*)d_in[11];
    const float* wd_un   = (const float*)d_in[12];
    float* out = (float*)d_out;

    const int N = in_sizes[0] / 3;          // q_pts is [N,3]
    const int blocks = (N + 3) / 4;         // 1 wave per point, 4 points/block
    areconv_kernel<<<blocks, 256, 0, stream>>>(
        q_pts, s_pts, nbr, wb, w_vn, wd_vn, w_h1, w_h2, b_h2,
        wd_relu, w_un, wd_un, out, N);
}

// Round 4
// 127.212 us; speedup vs baseline: 1.1837x; 1.0106x over previous
//
#include <hip/hip_runtime.h>
#include <math.h>

#define VN_EPS   1e-6f
#define NEG      0.2f
#define POS      0.8f   // 1 - NEG

typedef float v2f __attribute__((ext_vector_type(2)));
typedef float v4f __attribute__((ext_vector_type(4)));

// ---- DPP 16-lane (row) reductions: VALU-only --------------------------------
template <int CTRL>
__device__ __forceinline__ float dpp_add(float v) {
    int s = __builtin_amdgcn_update_dpp(0, __float_as_int(v), CTRL, 0xf, 0xf, true);
    return v + __int_as_float(s);
}
// all 16 lanes of the row end with the row sum (rotate butterfly)
__device__ __forceinline__ float row16_allsum(float v) {
    v = dpp_add<0x128>(v);  // row_ror:8
    v = dpp_add<0x124>(v);  // row_ror:4
    v = dpp_add<0x122>(v);  // row_ror:2
    v = dpp_add<0x121>(v);  // row_ror:1
    return v;
}
// row sum accumulates into lane 15 of the row (shift tree) — HW-verified R3
__device__ __forceinline__ float row16_sum15(float v) {
    v = dpp_add<0x118>(v);  // row_shr:8
    v = dpp_add<0x114>(v);  // row_shr:4
    v = dpp_add<0x112>(v);  // row_shr:2
    v = dpp_add<0x111>(v);  // row_shr:1
    return v;
}

// one wave = one point. lane = g*16 + k: k = neighbor (0..15), g = quarter (0..3).
__global__ __launch_bounds__(256, 4) void areconv_kernel(
    const float* __restrict__ q_pts,    // [N,3]
    const float* __restrict__ s_pts,    // [N2,3]
    const int*   __restrict__ nbr,      // [N,16]
    const float* __restrict__ wb,       // [3,256]
    const float* __restrict__ w_vn,     // [3,16]
    const float* __restrict__ wd_vn,    // [3,16]
    const float* __restrict__ w_h1,     // [16,8]
    const float* __restrict__ w_h2,     // [8,8]
    const float* __restrict__ b_h2,     // [8]
    const float* __restrict__ wd_relu,  // [32,32]
    const float* __restrict__ w_un,     // [32,64]
    const float* __restrict__ wd_un,    // [32,64]
    float* __restrict__ out,            // [N,64,3]
    int N)
{
    const float BN_SCALE = 0.999994993f;  // float32(1/sqrt(1+1e-5))

    // d-major per-point staging: [wave][d][h], stride 36 floats (144 B, 16B-mult
    // so v4f at h%4==0 is aligned). All producer->consumer intra-wave.
    __shared__ float featsA [4][3][36];
    __shared__ float feats2A[4][3][36];

    const int tid  = threadIdx.x;
    const int wv   = tid >> 6;
    const int lane = tid & 63;
    const int g    = (tid >> 4) & 3;  // quarter group 0..3
    const int k    = tid & 15;        // neighbor index
    const int n    = blockIdx.x * 4 + wv;
    if (n >= N) return;               // wave-uniform exit, no barriers anywhere

    // ---- gather + center + cross -> local frame L[c][d] ------------------
    const float qx = q_pts[n * 3 + 0];
    const float qy = q_pts[n * 3 + 1];
    const float qz = q_pts[n * 3 + 2];
    const int   id = nbr[n * 16 + k];
    const float px = s_pts[id * 3 + 0] - qx;
    const float py = s_pts[id * 3 + 1] - qy;
    const float pz = s_pts[id * 3 + 2] - qz;

    const float cx = row16_allsum(px) * 0.0625f;
    const float cy = row16_allsum(py) * 0.0625f;
    const float cz = row16_allsum(pz) * 0.0625f;

    const float rx = py * cz - pz * cy;
    const float ry = pz * cx - px * cz;
    const float rz = px * cy - py * cx;

    const float L[3][3] = {{px, py, pz}, {cx, cy, cz}, {rx, ry, rz}};

    // ---- score net: VNLinearLeakyReLU(3->16) -> ||.||, lane (g,k) does
    //      channels o = 4g..4g+3 -------------------------------------------
    float sn_loc[4];
#pragma unroll
    for (int j = 0; j < 4; ++j) {
        const int o = g * 4 + j;
        const float wv0 = w_vn[o],  wv1 = w_vn[16 + o],  wv2 = w_vn[32 + o];
        const float wd0 = wd_vn[o], wd1 = wd_vn[16 + o], wd2 = wd_vn[32 + o];
        float pv[3], dv[3];
        float dot = 0.f, dsq = 0.f;
#pragma unroll
        for (int d = 0; d < 3; ++d) {
            const float pp = BN_SCALE * (L[0][d] * wv0 + L[1][d] * wv1 + L[2][d] * wv2);
            const float dd = L[0][d] * wd0 + L[1][d] * wd1 + L[2][d] * wd2;
            pv[d] = pp; dv[d] = dd;
            dot += pp * dd;
            dsq += dd * dd;
        }
        const float f = dot * __builtin_amdgcn_rcpf(dsq + VN_EPS);
        float acc = 0.f;
#pragma unroll
        for (int d = 0; d < 3; ++d) {
            const float corr = pv[d] - f * dv[d];
            const float sel  = (dot >= 0.f) ? pv[d] : corr;
            const float a    = NEG * pv[d] + POS * sel;
            acc += a * a;
        }
        sn_loc[j] = __builtin_amdgcn_sqrtf(acc);
    }

    // ---- 16->8 conv (packed o-pairs): partials over this lane's 4 channels,
    //      reduce across the 4 rows (cross-row -> shfl) --------------------
    float tt[8];
#pragma unroll
    for (int op = 0; op < 4; ++op) {
        v2f t = sn_loc[0] * (*(const v2f*)&w_h1[(g * 4 + 0) * 8 + 2 * op])
              + sn_loc[1] * (*(const v2f*)&w_h1[(g * 4 + 1) * 8 + 2 * op])
              + sn_loc[2] * (*(const v2f*)&w_h1[(g * 4 + 2) * 8 + 2 * op])
              + sn_loc[3] * (*(const v2f*)&w_h1[(g * 4 + 3) * 8 + 2 * op]);
        float t0 = t[0], t1 = t[1];
        t0 += __shfl_xor(t0, 16);  t0 += __shfl_xor(t0, 32);
        t1 += __shfl_xor(t1, 16);  t1 += __shfl_xor(t1, 32);
        tt[2 * op + 0] = fmaxf(t0 * BN_SCALE, 0.f);
        tt[2 * op + 1] = fmaxf(t1 * BN_SCALE, 0.f);
    }

    // ---- 8->8 conv + bias (packed o-pairs), softmax ----------------------
    float sc[8];
    float mx = -1e30f;
#pragma unroll
    for (int op = 0; op < 4; ++op) {
        v2f u = *(const v2f*)&b_h2[2 * op];
#pragma unroll
        for (int c = 0; c < 8; ++c)
            u += tt[c] * (*(const v2f*)&w_h2[c * 8 + 2 * op]);
        sc[2 * op + 0] = u[0];
        sc[2 * op + 1] = u[1];
        mx = fmaxf(mx, fmaxf(u[0], u[1]));
    }
    float se = 0.f;
#pragma unroll
    for (int o = 0; o < 8; ++o) { sc[o] = __expf(sc[o] - mx); se += sc[o]; }
    const float inv_se = __builtin_amdgcn_rcpf(se);
#pragma unroll
    for (int o = 0; o < 8; ++o) sc[o] *= inv_se;

    // ---- kernel-point correlation, 4 h at a time (float4 / pk math).
    //      lane (g,k) handles h = 8g..8g+7 as two groups of 4. -------------
#pragma unroll
    for (int pg = 0; pg < 2; ++pg) {
        const int hb = g * 8 + pg * 4;
        v4f W0 = sc[0] * (*(const v4f*)&wb[0 * 256 + hb]);
        v4f W1 = sc[0] * (*(const v4f*)&wb[1 * 256 + hb]);
        v4f W2 = sc[0] * (*(const v4f*)&wb[2 * 256 + hb]);
#pragma unroll
        for (int s = 1; s < 8; ++s) {
            const float sv = sc[s];
            W0 += sv * (*(const v4f*)&wb[0 * 256 + s * 32 + hb]);
            W1 += sv * (*(const v4f*)&wb[1 * 256 + s * 32 + hb]);
            W2 += sv * (*(const v4f*)&wb[2 * 256 + s * 32 + hb]);
        }
        v4f V0 = L[0][0] * W0 + L[1][0] * W1 + L[2][0] * W2;
        v4f V1 = L[0][1] * W0 + L[1][1] * W1 + L[2][1] * W2;
        v4f V2 = L[0][2] * W0 + L[1][2] * W1 + L[2][2] * W2;
        v4f vv = V0 * V0 + V1 * V1 + V2 * V2;
        v4f inn;
#pragma unroll
        for (int e = 0; e < 4; ++e)
            inn[e] = __builtin_amdgcn_rsqf(fmaxf(vv[e], 1e-24f)) * 0.0625f; // 1/||v|| * mean
        V0 *= inn; V1 *= inn; V2 *= inn;
        v4f X0, X1, X2;
#pragma unroll
        for (int e = 0; e < 4; ++e) {
            X0[e] = row16_sum15(V0[e]);
            X1[e] = row16_sum15(V1[e]);
            X2[e] = row16_sum15(V2[e]);
        }
        if (k == 15) {
            *(v4f*)&featsA[wv][0][hb] = X0;
            *(v4f*)&featsA[wv][1][hb] = X1;
            *(v4f*)&featsA[wv][2][hb] = X2;
        }
    }
    // intra-wave LDS write->read (in-order DS pipe + compiler lgkmcnt)

    // ---- VNLeakyReLU(32->32): o = lane/2, h-range split by parity, v4f ----
    {
        const int o    = lane >> 1;
        const int half = lane & 1;
        v4f a0 = {0.f, 0.f, 0.f, 0.f}, a1 = a0, a2 = a0;
#pragma unroll
        for (int grp = 0; grp < 4; ++grp) {
            const int hb = half * 16 + grp * 4;
            const v4f w4 = { wd_relu[(hb + 0) * 32 + o], wd_relu[(hb + 1) * 32 + o],
                             wd_relu[(hb + 2) * 32 + o], wd_relu[(hb + 3) * 32 + o] };
            a0 += (*(const v4f*)&featsA[wv][0][hb]) * w4;
            a1 += (*(const v4f*)&featsA[wv][1][hb]) * w4;
            a2 += (*(const v4f*)&featsA[wv][2][hb]) * w4;
        }
        float d0 = a0[0] + a0[1] + a0[2] + a0[3];
        float d1 = a1[0] + a1[1] + a1[2] + a1[3];
        float d2 = a2[0] + a2[1] + a2[2] + a2[3];
        d0 += __shfl_xor(d0, 1);
        d1 += __shfl_xor(d1, 1);
        d2 += __shfl_xor(d2, 1);
        const float p0 = featsA[wv][0][o];
        const float p1 = featsA[wv][1][o];
        const float p2 = featsA[wv][2][o];
        const float dot = p0 * d0 + p1 * d1 + p2 * d2;
        const float dsq = d0 * d0 + d1 * d1 + d2 * d2;
        const float f   = dot * __builtin_amdgcn_rcpf(dsq + VN_EPS);
        const bool  pos = (dot >= 0.f);
        if (half == 0) {
            feats2A[wv][0][o] = NEG * p0 + POS * (pos ? p0 : (p0 - f * d0));
            feats2A[wv][1][o] = NEG * p1 + POS * (pos ? p1 : (p1 - f * d1));
            feats2A[wv][2][o] = NEG * p2 + POS * (pos ? p2 : (p2 - f * d2));
        }
    }

    // ---- VNLinearLeakyReLU(32->64): o = lane, v4f over h-groups ----------
    {
        const int o = lane;
        v4f au0 = {0.f, 0.f, 0.f, 0.f}, au1 = au0, au2 = au0;
        v4f av0 = au0, av1 = au0, av2 = au0;
#pragma unroll
        for (int grp = 0; grp < 8; ++grp) {
            const int hb = grp * 4;
            const v4f f0 = *(const v4f*)&feats2A[wv][0][hb];
            const v4f f1 = *(const v4f*)&feats2A[wv][1][hb];
            const v4f f2 = *(const v4f*)&feats2A[wv][2][hb];
            const v4f wu = { w_un[(hb + 0) * 64 + o], w_un[(hb + 1) * 64 + o],
                             w_un[(hb + 2) * 64 + o], w_un[(hb + 3) * 64 + o] };
            const v4f wd = { wd_un[(hb + 0) * 64 + o], wd_un[(hb + 1) * 64 + o],
                             wd_un[(hb + 2) * 64 + o], wd_un[(hb + 3) * 64 + o] };
            au0 += f0 * wu; au1 += f1 * wu; au2 += f2 * wu;
            av0 += f0 * wd; av1 += f1 * wd; av2 += f2 * wd;
        }
        float u0 = (au0[0] + au0[1] + au0[2] + au0[3]) * BN_SCALE;
        float u1 = (au1[0] + au1[1] + au1[2] + au1[3]) * BN_SCALE;
        float u2 = (au2[0] + au2[1] + au2[2] + au2[3]) * BN_SCALE;
        float v0 = av0[0] + av0[1] + av0[2] + av0[3];
        float v1 = av1[0] + av1[1] + av1[2] + av1[3];
        float v2 = av2[0] + av2[1] + av2[2] + av2[3];
        const float dot = u0 * v0 + u1 * v1 + u2 * v2;
        const float dsq = v0 * v0 + v1 * v1 + v2 * v2;
        const float f   = dot * __builtin_amdgcn_rcpf(dsq + VN_EPS);
        const bool  pos = (dot >= 0.f);
        const long  base = (long)n * 192 + o * 3;
        out[base + 0] = NEG * u0 + POS * (pos ? u0 : (u0 - f * v0));
        out[base + 1] = NEG * u1 + POS * (pos ? u1 : (u1 - f * v1));
        out[base + 2] = NEG * u2 + POS * (pos ? u2 : (u2 - f * v2));
    }
}

extern "C" void kernel_launch(void* const* d_in, const int* in_sizes, int n_in,
                              void* d_out, int out_size, void* d_ws, size_t ws_size,
                              hipStream_t stream) {
    const float* q_pts   = (const float*)d_in[0];
    const float* s_pts   = (const float*)d_in[1];
    // d_in[2] = s_feats: unused by the reference
    const int*   nbr     = (const int*)  d_in[3];
    const float* wb      = (const float*)d_in[4];
    const float* w_vn    = (const float*)d_in[5];
    const float* wd_vn   = (const float*)d_in[6];
    const float* w_h1    = (const float*)d_in[7];
    const float* w_h2    = (const float*)d_in[8];
    const float* b_h2    = (const float*)d_in[9];
    const float* wd_relu = (const float*)d_in[10];
    const float* w_un    = (const float*)d_in[11];
    const float* wd_un   = (const float*)d_in[12];
    float* out = (float*)d_out;

    const int N = in_sizes[0] / 3;          // q_pts is [N,3]
    const int blocks = (N + 3) / 4;         // 1 wave per point, 4 points/block
    areconv_kernel<<<blocks, 256, 0, stream>>>(
        q_pts, s_pts, nbr, wb, w_vn, wd_vn, w_h1, w_h2, b_h2,
        wd_relu, w_un, wd_un, out, N);
}

// Round 5
// 108.711 us; speedup vs baseline: 1.3851x; 1.1702x over previous
//
#include <hip/hip_runtime.h>
#include <math.h>

#define VN_EPS   1e-6f
#define NEG      0.2f
#define POS      0.8f   // 1 - NEG

typedef float v2f __attribute__((ext_vector_type(2)));
typedef float v4f __attribute__((ext_vector_type(4)));

// ---- DPP 16-lane (row) reductions: VALU-only, HW-verified R3/R4 ------------
template <int CTRL>
__device__ __forceinline__ float dpp_add(float v) {
    int s = __builtin_amdgcn_update_dpp(0, __float_as_int(v), CTRL, 0xf, 0xf, true);
    return v + __int_as_float(s);
}
// all 16 lanes of the row end with the row sum (rotate butterfly)
__device__ __forceinline__ float row16_allsum(float v) {
    v = dpp_add<0x128>(v);  // row_ror:8
    v = dpp_add<0x124>(v);  // row_ror:4
    v = dpp_add<0x122>(v);  // row_ror:2
    v = dpp_add<0x121>(v);  // row_ror:1
    return v;
}
// row sum accumulates into lane 15 of the row (shift tree)
__device__ __forceinline__ float row16_sum15(float v) {
    v = dpp_add<0x118>(v);  // row_shr:8
    v = dpp_add<0x114>(v);  // row_shr:4
    v = dpp_add<0x112>(v);  // row_shr:2
    v = dpp_add<0x111>(v);  // row_shr:1
    return v;
}

__device__ __forceinline__ float hsum4(v4f a) {
    return (a[0] + a[1]) + (a[2] + a[3]);
}

// ONE WAVE PER BLOCK, FOUR POINTS PER WAVE.
// lane = p*16 + k: p = point-in-wave (0..3) = DPP row, k = neighbor (0..15).
// Per-wave fixed overhead (preamble, gather chain, weight batches, LDS
// round-trips) is amortized over 4 points — attacks the measured ~24k-cycle
// wave lifetime at ~4k cycles of issue (R4 counters).
__global__ __launch_bounds__(64, 4) void areconv_kernel(
    const float* __restrict__ q_pts,    // [N,3]
    const float* __restrict__ s_pts,    // [N2,3]
    const int*   __restrict__ nbr,      // [N,16]
    const float* __restrict__ wb,       // [3,256]
    const float* __restrict__ w_vn,     // [3,16]
    const float* __restrict__ wd_vn,    // [3,16]
    const float* __restrict__ w_h1,     // [16,8]
    const float* __restrict__ w_h2,     // [8,8]
    const float* __restrict__ b_h2,     // [8]
    const float* __restrict__ wd_relu,  // [32,32]
    const float* __restrict__ w_un,     // [32,64]
    const float* __restrict__ wd_un,    // [32,64]
    float* __restrict__ out,            // [N,64,3]
    int N)
{
    const float BN_SCALE = 0.999994993f;  // float32(1/sqrt(1+1e-5))

    // per-point staging, d-major: [point][d][h], stride 36 floats (144 B,
    // 16B-multiple so v4f at h%4==0 aligned). All intra-wave producer->consumer.
    __shared__ float featsA [4][3][36];
    __shared__ float feats2A[4][3][36];

    const int lane = threadIdx.x & 63;
    const int p    = lane >> 4;       // DPP row = point slot in wave
    const int k    = lane & 15;       // neighbor index
    int n = blockIdx.x * 4 + p;
    n = (n < N) ? n : (N - 1);        // dup-compute guard (N%4==0 -> no dups)

    // ---- gather + center + cross -> local frame L[c][d] ------------------
    const float qx = q_pts[n * 3 + 0];
    const float qy = q_pts[n * 3 + 1];
    const float qz = q_pts[n * 3 + 2];
    const int   id = nbr[n * 16 + k];
    const float px = s_pts[id * 3 + 0] - qx;
    const float py = s_pts[id * 3 + 1] - qy;
    const float pz = s_pts[id * 3 + 2] - qz;

    const float cx = row16_allsum(px) * 0.0625f;
    const float cy = row16_allsum(py) * 0.0625f;
    const float cz = row16_allsum(pz) * 0.0625f;

    const float rx = py * cz - pz * cy;
    const float ry = pz * cx - px * cz;
    const float rz = px * cy - py * cx;

    const float L[3][3] = {{px, py, pz}, {cx, cy, cz}, {rx, ry, rz}};

    // ---- score net: VNLinearLeakyReLU(3->16) -> ||.||, all 16 channels
    //      lane-local (weights at compile-time offsets -> SMEM-promotable) --
    float sn[16];
#pragma unroll
    for (int o = 0; o < 16; ++o) {
        const float wv0 = w_vn[o],  wv1 = w_vn[16 + o],  wv2 = w_vn[32 + o];
        const float wd0 = wd_vn[o], wd1 = wd_vn[16 + o], wd2 = wd_vn[32 + o];
        float pv[3], dv[3];
        float dot = 0.f, dsq = 0.f;
#pragma unroll
        for (int d = 0; d < 3; ++d) {
            const float pp = BN_SCALE * (L[0][d] * wv0 + L[1][d] * wv1 + L[2][d] * wv2);
            const float dd = L[0][d] * wd0 + L[1][d] * wd1 + L[2][d] * wd2;
            pv[d] = pp; dv[d] = dd;
            dot += pp * dd;
            dsq += dd * dd;
        }
        const float f = dot * __builtin_amdgcn_rcpf(dsq + VN_EPS);
        float acc = 0.f;
#pragma unroll
        for (int d = 0; d < 3; ++d) {
            const float corr = pv[d] - f * dv[d];
            const float sel  = (dot >= 0.f) ? pv[d] : corr;
            const float a    = NEG * pv[d] + POS * sel;
            acc += a * a;
        }
        sn[o] = __builtin_amdgcn_sqrtf(acc);
    }

    // ---- 16->8 conv + BN + relu: fully lane-local, zero cross-lane -------
    float tt[8];
#pragma unroll
    for (int op = 0; op < 4; ++op) {
        v2f t = {0.f, 0.f};
#pragma unroll
        for (int c = 0; c < 16; ++c)
            t += sn[c] * (*(const v2f*)&w_h1[c * 8 + 2 * op]);
        tt[2 * op + 0] = fmaxf(t[0] * BN_SCALE, 0.f);
        tt[2 * op + 1] = fmaxf(t[1] * BN_SCALE, 0.f);
    }

    // ---- 8->8 conv + bias, softmax over channels -------------------------
    float sc[8];
    float mx = -1e30f;
#pragma unroll
    for (int op = 0; op < 4; ++op) {
        v2f u = *(const v2f*)&b_h2[2 * op];
#pragma unroll
        for (int c = 0; c < 8; ++c)
            u += tt[c] * (*(const v2f*)&w_h2[c * 8 + 2 * op]);
        sc[2 * op + 0] = u[0];
        sc[2 * op + 1] = u[1];
        mx = fmaxf(mx, fmaxf(u[0], u[1]));
    }
    float se = 0.f;
#pragma unroll
    for (int o = 0; o < 8; ++o) { sc[o] = __expf(sc[o] - mx); se += sc[o]; }
    const float inv_se = __builtin_amdgcn_rcpf(se);
#pragma unroll
    for (int o = 0; o < 8; ++o) sc[o] *= inv_se;

    // ---- kernel-point correlation: each lane does ALL 32 h (8 v4f groups)
    //      for its own k; mean over k via per-row DPP tree -> lane k=15 ----
#pragma unroll
    for (int grp = 0; grp < 8; ++grp) {
        const int hb = grp * 4;   // compile-time -> wb loads uniform/SMEM-able
        v4f W0 = sc[0] * (*(const v4f*)&wb[0 * 256 + hb]);
        v4f W1 = sc[0] * (*(const v4f*)&wb[1 * 256 + hb]);
        v4f W2 = sc[0] * (*(const v4f*)&wb[2 * 256 + hb]);
#pragma unroll
        for (int s = 1; s < 8; ++s) {
            const float sv = sc[s];
            W0 += sv * (*(const v4f*)&wb[0 * 256 + s * 32 + hb]);
            W1 += sv * (*(const v4f*)&wb[1 * 256 + s * 32 + hb]);
            W2 += sv * (*(const v4f*)&wb[2 * 256 + s * 32 + hb]);
        }
        v4f V0 = L[0][0] * W0 + L[1][0] * W1 + L[2][0] * W2;
        v4f V1 = L[0][1] * W0 + L[1][1] * W1 + L[2][1] * W2;
        v4f V2 = L[0][2] * W0 + L[1][2] * W1 + L[2][2] * W2;
        v4f vv = V0 * V0 + V1 * V1 + V2 * V2;
        v4f inn;
#pragma unroll
        for (int e = 0; e < 4; ++e)
            inn[e] = __builtin_amdgcn_rsqf(fmaxf(vv[e], 1e-24f)) * 0.0625f; // 1/||v|| * (1/16)
        V0 *= inn; V1 *= inn; V2 *= inn;
        v4f X0, X1, X2;
#pragma unroll
        for (int e = 0; e < 4; ++e) {
            X0[e] = row16_sum15(V0[e]);
            X1[e] = row16_sum15(V1[e]);
            X2[e] = row16_sum15(V2[e]);
        }
        if (k == 15) {
            *(v4f*)&featsA[p][0][hb] = X0;
            *(v4f*)&featsA[p][1][hb] = X1;
            *(v4f*)&featsA[p][2][hb] = X2;
        }
    }
    // intra-wave LDS write->read (in-order DS pipe + compiler lgkmcnt)

    // ---- VNLeakyReLU(32->32): lane handles o = k, k+16 for its point -----
    {
        v4f a0[2], a1[2], a2[2];
#pragma unroll
        for (int j = 0; j < 2; ++j) { a0[j] = (v4f)0.f; a1[j] = (v4f)0.f; a2[j] = (v4f)0.f; }
#pragma unroll
        for (int grp = 0; grp < 8; ++grp) {
            const int hb = grp * 4;
            const v4f f0 = *(const v4f*)&featsA[p][0][hb];
            const v4f f1 = *(const v4f*)&featsA[p][1][hb];
            const v4f f2 = *(const v4f*)&featsA[p][2][hb];
#pragma unroll
            for (int j = 0; j < 2; ++j) {
                const int o = k + 16 * j;
                const v4f w4 = { wd_relu[(hb + 0) * 32 + o], wd_relu[(hb + 1) * 32 + o],
                                 wd_relu[(hb + 2) * 32 + o], wd_relu[(hb + 3) * 32 + o] };
                a0[j] += f0 * w4;
                a1[j] += f1 * w4;
                a2[j] += f2 * w4;
            }
        }
#pragma unroll
        for (int j = 0; j < 2; ++j) {
            const int o = k + 16 * j;
            const float d0 = hsum4(a0[j]);
            const float d1 = hsum4(a1[j]);
            const float d2 = hsum4(a2[j]);
            const float p0 = featsA[p][0][o];
            const float p1 = featsA[p][1][o];
            const float p2 = featsA[p][2][o];
            const float dot = p0 * d0 + p1 * d1 + p2 * d2;
            const float dsq = d0 * d0 + d1 * d1 + d2 * d2;
            const float f   = dot * __builtin_amdgcn_rcpf(dsq + VN_EPS);
            const bool  pos = (dot >= 0.f);
            feats2A[p][0][o] = NEG * p0 + POS * (pos ? p0 : (p0 - f * d0));
            feats2A[p][1][o] = NEG * p1 + POS * (pos ? p1 : (p1 - f * d1));
            feats2A[p][2][o] = NEG * p2 + POS * (pos ? p2 : (p2 - f * d2));
        }
    }

    // ---- VNLinearLeakyReLU(32->64): lane handles o = k+16j, j=0..3 -------
#pragma unroll
    for (int j = 0; j < 4; ++j) {
        const int o = k + 16 * j;
        v4f au0 = (v4f)0.f, au1 = (v4f)0.f, au2 = (v4f)0.f;
        v4f av0 = (v4f)0.f, av1 = (v4f)0.f, av2 = (v4f)0.f;
#pragma unroll
        for (int grp = 0; grp < 8; ++grp) {
            const int hb = grp * 4;
            const v4f f0 = *(const v4f*)&feats2A[p][0][hb];
            const v4f f1 = *(const v4f*)&feats2A[p][1][hb];
            const v4f f2 = *(const v4f*)&feats2A[p][2][hb];
            const v4f wu = { w_un[(hb + 0) * 64 + o], w_un[(hb + 1) * 64 + o],
                             w_un[(hb + 2) * 64 + o], w_un[(hb + 3) * 64 + o] };
            const v4f wd = { wd_un[(hb + 0) * 64 + o], wd_un[(hb + 1) * 64 + o],
                             wd_un[(hb + 2) * 64 + o], wd_un[(hb + 3) * 64 + o] };
            au0 += f0 * wu; au1 += f1 * wu; au2 += f2 * wu;
            av0 += f0 * wd; av1 += f1 * wd; av2 += f2 * wd;
        }
        float u0 = hsum4(au0) * BN_SCALE;
        float u1 = hsum4(au1) * BN_SCALE;
        float u2 = hsum4(au2) * BN_SCALE;
        float v0 = hsum4(av0);
        float v1 = hsum4(av1);
        float v2 = hsum4(av2);
        const float dot = u0 * v0 + u1 * v1 + u2 * v2;
        const float dsq = v0 * v0 + v1 * v1 + v2 * v2;
        const float f   = dot * __builtin_amdgcn_rcpf(dsq + VN_EPS);
        const bool  pos = (dot >= 0.f);
        const long  base = (long)n * 192 + o * 3;
        out[base + 0] = NEG * u0 + POS * (pos ? u0 : (u0 - f * v0));
        out[base + 1] = NEG * u1 + POS * (pos ? u1 : (u1 - f * v1));
        out[base + 2] = NEG * u2 + POS * (pos ? u2 : (u2 - f * v2));
    }
}

extern "C" void kernel_launch(void* const* d_in, const int* in_sizes, int n_in,
                              void* d_out, int out_size, void* d_ws, size_t ws_size,
                              hipStream_t stream) {
    const float* q_pts   = (const float*)d_in[0];
    const float* s_pts   = (const float*)d_in[1];
    // d_in[2] = s_feats: unused by the reference
    const int*   nbr     = (const int*)  d_in[3];
    const float* wb      = (const float*)d_in[4];
    const float* w_vn    = (const float*)d_in[5];
    const float* wd_vn   = (const float*)d_in[6];
    const float* w_h1    = (const float*)d_in[7];
    const float* w_h2    = (const float*)d_in[8];
    const float* b_h2    = (const float*)d_in[9];
    const float* wd_relu = (const float*)d_in[10];
    const float* w_un    = (const float*)d_in[11];
    const float* wd_un   = (const float*)d_in[12];
    float* out = (float*)d_out;

    const int N = in_sizes[0] / 3;          // q_pts is [N,3]
    const int blocks = (N + 3) / 4;         // 1 wave per block, 4 points/wave
    areconv_kernel<<<blocks, 64, 0, stream>>>(
        q_pts, s_pts, nbr, wb, w_vn, wd_vn, w_h1, w_h2, b_h2,
        wd_relu, w_un, wd_un, out, N);
}

// Round 7
// 108.184 us; speedup vs baseline: 1.3919x; 1.0049x over previous
//
#include <hip/hip_runtime.h>
#include <math.h>

#define VN_EPS   1e-6f
#define NEG      0.2f
#define POS      0.8f   // 1 - NEG

typedef float v2f __attribute__((ext_vector_type(2)));
typedef float v4f __attribute__((ext_vector_type(4)));

// ---- DPP 16-lane (row) reductions: VALU-only, HW-verified R3/R5 ------------
template <int CTRL>
__device__ __forceinline__ float dpp_add(float v) {
    int s = __builtin_amdgcn_update_dpp(0, __float_as_int(v), CTRL, 0xf, 0xf, true);
    return v + __int_as_float(s);
}
// all 16 lanes of the row end with the row sum (rotate butterfly)
__device__ __forceinline__ float row16_allsum(float v) {
    v = dpp_add<0x128>(v);  // row_ror:8
    v = dpp_add<0x124>(v);  // row_ror:4
    v = dpp_add<0x122>(v);  // row_ror:2
    v = dpp_add<0x121>(v);  // row_ror:1
    return v;
}
// row sum accumulates into lane 15 of the row (shift tree)
__device__ __forceinline__ float row16_sum15(float v) {
    v = dpp_add<0x118>(v);  // row_shr:8
    v = dpp_add<0x114>(v);  // row_shr:4
    v = dpp_add<0x112>(v);  // row_shr:2
    v = dpp_add<0x111>(v);  // row_shr:1
    return v;
}

// 4 points per wave (lane = p*16 + k), 4 waves/block -> 16 points per block.
// NOTE (R6 post-mortem): scores sc[] are PER-NEIGHBOR (per-lane) — the
// score-fold W(h) must be computed per lane; it is NOT row-uniform. Do not
// re-introduce the R6 LDS dedup.
__global__ __launch_bounds__(256, 4) void areconv_kernel(
    const float* __restrict__ q_pts,    // [N,3]
    const float* __restrict__ s_pts,    // [N2,3]
    const int*   __restrict__ nbr,      // [N,16]
    const float* __restrict__ wb,       // [3,256]
    const float* __restrict__ w_vn,     // [3,16]
    const float* __restrict__ wd_vn,    // [3,16]
    const float* __restrict__ w_h1,     // [16,8]
    const float* __restrict__ w_h2,     // [8,8]
    const float* __restrict__ b_h2,     // [8]
    const float* __restrict__ wd_relu,  // [32,32]
    const float* __restrict__ w_un,     // [32,64]
    const float* __restrict__ wd_un,    // [32,64]
    float* __restrict__ out,            // [N,64,3]
    int N)
{
    const float BN_SCALE = 0.999994993f;  // float32(1/sqrt(1+1e-5))

    // per-point staging, d-major [bp][d][h], stride 36 floats (144 B = 16B
    // multiple, v4f-aligned at h%4==0). All traffic intra-wave (lanes of wave
    // wv touch only bp in [4wv,4wv+4)) -> in-order DS pipe + compiler lgkmcnt,
    // no barriers (pattern HW-validated in R4/R5).
    __shared__ __align__(16) float featsA [16][3][36];
    __shared__ __align__(16) float feats2A[16][3][36];

    const int tid  = threadIdx.x;
    const int wv   = tid >> 6;
    const int lane = tid & 63;
    const int p    = lane >> 4;       // DPP row = point-in-wave
    const int k    = lane & 15;       // neighbor index
    const int bp   = wv * 4 + p;      // point slot in block
    int n = blockIdx.x * 16 + bp;
    n = (n < N) ? n : (N - 1);        // N=16000 -> never clamps

    // ---- gather + center + cross -> local frame L[c][d] ------------------
    const float qx = q_pts[n * 3 + 0];
    const float qy = q_pts[n * 3 + 1];
    const float qz = q_pts[n * 3 + 2];
    const int   id = nbr[n * 16 + k];
    const float px = s_pts[id * 3 + 0] - qx;
    const float py = s_pts[id * 3 + 1] - qy;
    const float pz = s_pts[id * 3 + 2] - qz;

    const float cx = row16_allsum(px) * 0.0625f;
    const float cy = row16_allsum(py) * 0.0625f;
    const float cz = row16_allsum(pz) * 0.0625f;

    const float rx = py * cz - pz * cy;
    const float ry = pz * cx - px * cz;
    const float rz = px * cy - py * cx;

    const float L[3][3] = {{px, py, pz}, {cx, cy, cz}, {rx, ry, rz}};

    // ---- score net: VNLinearLeakyReLU(3->16) -> ||.||, lane-local --------
    float sn[16];
#pragma unroll
    for (int o = 0; o < 16; ++o) {
        const float wv0 = w_vn[o],  wv1 = w_vn[16 + o],  wv2 = w_vn[32 + o];
        const float wd0 = wd_vn[o], wd1 = wd_vn[16 + o], wd2 = wd_vn[32 + o];
        float pv[3], dv[3];
        float dot = 0.f, dsq = 0.f;
#pragma unroll
        for (int d = 0; d < 3; ++d) {
            const float pp = BN_SCALE * (L[0][d] * wv0 + L[1][d] * wv1 + L[2][d] * wv2);
            const float dd = L[0][d] * wd0 + L[1][d] * wd1 + L[2][d] * wd2;
            pv[d] = pp; dv[d] = dd;
            dot += pp * dd;
            dsq += dd * dd;
        }
        const float f = dot * __builtin_amdgcn_rcpf(dsq + VN_EPS);
        float acc = 0.f;
#pragma unroll
        for (int d = 0; d < 3; ++d) {
            const float corr = pv[d] - f * dv[d];
            const float sel  = (dot >= 0.f) ? pv[d] : corr;
            const float a    = NEG * pv[d] + POS * sel;
            acc += a * a;
        }
        sn[o] = __builtin_amdgcn_sqrtf(acc);
    }

    // ---- 16->8 conv + BN + relu: lane-local ------------------------------
    float tt[8];
#pragma unroll
    for (int op = 0; op < 4; ++op) {
        v2f t = {0.f, 0.f};
#pragma unroll
        for (int c = 0; c < 16; ++c)
            t += sn[c] * (*(const v2f*)&w_h1[c * 8 + 2 * op]);
        tt[2 * op + 0] = fmaxf(t[0] * BN_SCALE, 0.f);
        tt[2 * op + 1] = fmaxf(t[1] * BN_SCALE, 0.f);
    }

    // ---- 8->8 conv + bias, softmax over channels -------------------------
    float sc[8];
    float mx = -1e30f;
#pragma unroll
    for (int op = 0; op < 4; ++op) {
        v2f u = *(const v2f*)&b_h2[2 * op];
#pragma unroll
        for (int c = 0; c < 8; ++c)
            u += tt[c] * (*(const v2f*)&w_h2[c * 8 + 2 * op]);
        sc[2 * op + 0] = u[0];
        sc[2 * op + 1] = u[1];
        mx = fmaxf(mx, fmaxf(u[0], u[1]));
    }
    float se = 0.f;
#pragma unroll
    for (int o = 0; o < 8; ++o) { sc[o] = __expf(sc[o] - mx); se += sc[o]; }
    const float inv_se = __builtin_amdgcn_rcpf(se);
#pragma unroll
    for (int o = 0; o < 8; ++o) sc[o] *= inv_se;

    // ---- kernel-point correlation: PER-LANE fold over scores (correct —
    //      sc is per-neighbor), project, normalize, mean over k ------------
#pragma unroll
    for (int grp = 0; grp < 8; ++grp) {
        const int hb = grp * 4;
        v4f W0 = sc[0] * (*(const v4f*)&wb[0 * 256 + hb]);
        v4f W1 = sc[0] * (*(const v4f*)&wb[1 * 256 + hb]);
        v4f W2 = sc[0] * (*(const v4f*)&wb[2 * 256 + hb]);
#pragma unroll
        for (int s = 1; s < 8; ++s) {
            const float sv = sc[s];
            W0 += sv * (*(const v4f*)&wb[0 * 256 + s * 32 + hb]);
            W1 += sv * (*(const v4f*)&wb[1 * 256 + s * 32 + hb]);
            W2 += sv * (*(const v4f*)&wb[2 * 256 + s * 32 + hb]);
        }
        v4f V0 = L[0][0] * W0 + L[1][0] * W1 + L[2][0] * W2;
        v4f V1 = L[0][1] * W0 + L[1][1] * W1 + L[2][1] * W2;
        v4f V2 = L[0][2] * W0 + L[1][2] * W1 + L[2][2] * W2;
        v4f vv = V0 * V0 + V1 * V1 + V2 * V2;
        v4f inn;
#pragma unroll
        for (int e = 0; e < 4; ++e)
            inn[e] = __builtin_amdgcn_rsqf(fmaxf(vv[e], 1e-24f)) * 0.0625f; // 1/||v|| * (1/16)
        V0 *= inn; V1 *= inn; V2 *= inn;
        v4f X0, X1, X2;
#pragma unroll
        for (int e = 0; e < 4; ++e) {
            X0[e] = row16_sum15(V0[e]);
            X1[e] = row16_sum15(V1[e]);
            X2[e] = row16_sum15(V2[e]);
        }
        if (k == 15) {
            *(v4f*)&featsA[bp][0][hb] = X0;
            *(v4f*)&featsA[bp][1][hb] = X1;
            *(v4f*)&featsA[bp][2][hb] = X2;
        }
    }
    // intra-wave LDS write->read (in-order DS pipe + compiler lgkmcnt)

    // ---- VNLeakyReLU(32->32): lane owns o = {2k, 2k+1}; v2f weight loads,
    //      o stays vectorized -> no hsum -----------------------------------
    {
        v2f D0 = {0.f, 0.f}, D1 = D0, D2 = D0;
#pragma unroll
        for (int grp = 0; grp < 8; ++grp) {
            const int hb = grp * 4;
            const v4f f0 = *(const v4f*)&featsA[bp][0][hb];
            const v4f f1 = *(const v4f*)&featsA[bp][1][hb];
            const v4f f2 = *(const v4f*)&featsA[bp][2][hb];
#pragma unroll
            for (int e = 0; e < 4; ++e) {
                const v2f w = *(const v2f*)&wd_relu[(hb + e) * 32 + 2 * k];
                D0 += f0[e] * w;
                D1 += f1[e] * w;
                D2 += f2[e] * w;
            }
        }
        v2f R0, R1, R2;
#pragma unroll
        for (int j = 0; j < 2; ++j) {
            const int o = 2 * k + j;
            const float p0 = featsA[bp][0][o];
            const float p1 = featsA[bp][1][o];
            const float p2 = featsA[bp][2][o];
            const float d0 = D0[j], d1 = D1[j], d2 = D2[j];
            const float dot = p0 * d0 + p1 * d1 + p2 * d2;
            const float dsq = d0 * d0 + d1 * d1 + d2 * d2;
            const float f   = dot * __builtin_amdgcn_rcpf(dsq + VN_EPS);
            const bool  pos = (dot >= 0.f);
            R0[j] = NEG * p0 + POS * (pos ? p0 : (p0 - f * d0));
            R1[j] = NEG * p1 + POS * (pos ? p1 : (p1 - f * d1));
            R2[j] = NEG * p2 + POS * (pos ? p2 : (p2 - f * d2));
        }
        *(v2f*)&feats2A[bp][0][2 * k] = R0;
        *(v2f*)&feats2A[bp][1][2 * k] = R1;
        *(v2f*)&feats2A[bp][2][2 * k] = R2;
    }

    // ---- VNLinearLeakyReLU(32->64): lane owns o = 4k..4k+3; dwordx4
    //      weight loads, v4f accumulators over o, coalesced x4 stores ------
    {
        v4f AU0 = (v4f)0.f, AU1 = AU0, AU2 = AU0;
        v4f AV0 = AU0, AV1 = AU0, AV2 = AU0;
#pragma unroll
        for (int grp = 0; grp < 8; ++grp) {
            const int hb = grp * 4;
            const v4f f0 = *(const v4f*)&feats2A[bp][0][hb];
            const v4f f1 = *(const v4f*)&feats2A[bp][1][hb];
            const v4f f2 = *(const v4f*)&feats2A[bp][2][hb];
#pragma unroll
            for (int e = 0; e < 4; ++e) {
                const v4f wu = *(const v4f*)&w_un [(hb + e) * 64 + 4 * k];
                const v4f wd = *(const v4f*)&wd_un[(hb + e) * 64 + 4 * k];
                AU0 += f0[e] * wu; AU1 += f1[e] * wu; AU2 += f2[e] * wu;
                AV0 += f0[e] * wd; AV1 += f1[e] * wd; AV2 += f2[e] * wd;
            }
        }
        float O[12];
#pragma unroll
        for (int e = 0; e < 4; ++e) {
            const float u0 = AU0[e] * BN_SCALE;
            const float u1 = AU1[e] * BN_SCALE;
            const float u2 = AU2[e] * BN_SCALE;
            const float v0 = AV0[e], v1 = AV1[e], v2 = AV2[e];
            const float dot = u0 * v0 + u1 * v1 + u2 * v2;
            const float dsq = v0 * v0 + v1 * v1 + v2 * v2;
            const float f   = dot * __builtin_amdgcn_rcpf(dsq + VN_EPS);
            const bool  pos = (dot >= 0.f);
            O[3 * e + 0] = NEG * u0 + POS * (pos ? u0 : (u0 - f * v0));
            O[3 * e + 1] = NEG * u1 + POS * (pos ? u1 : (u1 - f * v1));
            O[3 * e + 2] = NEG * u2 + POS * (pos ? u2 : (u2 - f * v2));
        }
        // lane k covers out[n, 4k..4k+4, :] = 12 contiguous floats; a row of
        // 16 lanes covers the point's whole 192-float slab contiguously.
        float* dst = out + (long)n * 192 + 12 * k;
        *(v4f*)(dst + 0) = *(const v4f*)&O[0];
        *(v4f*)(dst + 4) = *(const v4f*)&O[4];
        *(v4f*)(dst + 8) = *(const v4f*)&O[8];
    }
}

extern "C" void kernel_launch(void* const* d_in, const int* in_sizes, int n_in,
                              void* d_out, int out_size, void* d_ws, size_t ws_size,
                              hipStream_t stream) {
    const float* q_pts   = (const float*)d_in[0];
    const float* s_pts   = (const float*)d_in[1];
    // d_in[2] = s_feats: unused by the reference
    const int*   nbr     = (const int*)  d_in[3];
    const float* wb      = (const float*)d_in[4];
    const float* w_vn    = (const float*)d_in[5];
    const float* wd_vn   = (const float*)d_in[6];
    const float* w_h1    = (const float*)d_in[7];
    const float* w_h2    = (const float*)d_in[8];
    const float* b_h2    = (const float*)d_in[9];
    const float* wd_relu = (const float*)d_in[10];
    const float* w_un    = (const float*)d_in[11];
    const float* wd_un   = (const float*)d_in[12];
    float* out = (float*)d_out;

    const int N = in_sizes[0] / 3;          // q_pts is [N,3]
    const int blocks = (N + 15) / 16;       // 16 points/block, 4 per wave
    areconv_kernel<<<blocks, 256, 0, stream>>>(
        q_pts, s_pts, nbr, wb, w_vn, wd_vn, w_h1, w_h2, b_h2,
        wd_relu, w_un, wd_un, out, N);
}

// Round 8
// 108.044 us; speedup vs baseline: 1.3937x; 1.0013x over previous
//
#include <hip/hip_runtime.h>
#include <math.h>

#define VN_EPS   1e-6f
#define NEG      0.2f
#define POS      0.8f   // 1 - NEG

typedef float v2f __attribute__((ext_vector_type(2)));
typedef float v4f __attribute__((ext_vector_type(4)));

// ---- DPP 16-lane (row) reductions: VALU-only, HW-verified R3/R5/R7 ---------
template <int CTRL>
__device__ __forceinline__ float dpp_add(float v) {
    int s = __builtin_amdgcn_update_dpp(0, __float_as_int(v), CTRL, 0xf, 0xf, true);
    return v + __int_as_float(s);
}
// all 16 lanes of the row end with the row sum (rotate butterfly)
__device__ __forceinline__ float row16_allsum(float v) {
    v = dpp_add<0x128>(v);  // row_ror:8
    v = dpp_add<0x124>(v);  // row_ror:4
    v = dpp_add<0x122>(v);  // row_ror:2
    v = dpp_add<0x121>(v);  // row_ror:1
    return v;
}
// row sum accumulates into lane 15 of the row (shift tree)
__device__ __forceinline__ float row16_sum15(float v) {
    v = dpp_add<0x118>(v);  // row_shr:8
    v = dpp_add<0x114>(v);  // row_shr:4
    v = dpp_add<0x112>(v);  // row_shr:2
    v = dpp_add<0x111>(v);  // row_shr:1
    return v;
}

// 4 points per wave (lane = p*16 + k); 2 waves/block (128 thd) -> 8 points per
// block, 2000 WGs. R7 post-mortem: 1000×256-thd WGs caused ~33% load-imbalance
// tail (3.9 WGs/CU); R5's 4000×64-thd WGs hit the ~8 WG/CU slot cap at only
// 8 waves/CU. 128-thd is the midpoint: fine balance + up to 16 waves/CU.
// NOTE (R6): scores sc[] are PER-NEIGHBOR — the fold W(h) is per-lane, not
// row-uniform. Do not dedup it through LDS.
__global__ __launch_bounds__(128, 4) void areconv_kernel(
    const float* __restrict__ q_pts,    // [N,3]
    const float* __restrict__ s_pts,    // [N2,3]
    const int*   __restrict__ nbr,      // [N,16]
    const float* __restrict__ wb,       // [3,256]
    const float* __restrict__ w_vn,     // [3,16]
    const float* __restrict__ wd_vn,    // [3,16]
    const float* __restrict__ w_h1,     // [16,8]
    const float* __restrict__ w_h2,     // [8,8]
    const float* __restrict__ b_h2,     // [8]
    const float* __restrict__ wd_relu,  // [32,32]
    const float* __restrict__ w_un,     // [32,64]
    const float* __restrict__ wd_un,    // [32,64]
    float* __restrict__ out,            // [N,64,3]
    int N)
{
    const float BN_SCALE = 0.999994993f;  // float32(1/sqrt(1+1e-5))

    // per-point staging, d-major [bp][d][h], stride 36 floats (144 B = 16B
    // multiple, v4f-aligned at h%4==0). All traffic intra-wave (lanes of wave
    // wv touch only bp in [4wv,4wv+4)) -> in-order DS pipe + compiler lgkmcnt,
    // no barriers (pattern HW-validated R4-R7).
    __shared__ __align__(16) float featsA [8][3][36];
    __shared__ __align__(16) float feats2A[8][3][36];

    const int tid  = threadIdx.x;
    const int wv   = tid >> 6;        // 0..1
    const int lane = tid & 63;
    const int p    = lane >> 4;       // DPP row = point-in-wave
    const int k    = lane & 15;       // neighbor index
    const int bp   = wv * 4 + p;      // point slot in block (0..7)
    int n = blockIdx.x * 8 + bp;
    n = (n < N) ? n : (N - 1);        // N=16000 -> never clamps

    // ---- gather + center + cross -> local frame L[c][d] ------------------
    const float qx = q_pts[n * 3 + 0];
    const float qy = q_pts[n * 3 + 1];
    const float qz = q_pts[n * 3 + 2];
    const int   id = nbr[n * 16 + k];
    const float px = s_pts[id * 3 + 0] - qx;
    const float py = s_pts[id * 3 + 1] - qy;
    const float pz = s_pts[id * 3 + 2] - qz;

    const float cx = row16_allsum(px) * 0.0625f;
    const float cy = row16_allsum(py) * 0.0625f;
    const float cz = row16_allsum(pz) * 0.0625f;

    const float rx = py * cz - pz * cy;
    const float ry = pz * cx - px * cz;
    const float rz = px * cy - py * cx;

    const float L[3][3] = {{px, py, pz}, {cx, cy, cz}, {rx, ry, rz}};

    // ---- score net: VNLinearLeakyReLU(3->16) -> ||.||, lane-local --------
    float sn[16];
#pragma unroll
    for (int o = 0; o < 16; ++o) {
        const float wv0 = w_vn[o],  wv1 = w_vn[16 + o],  wv2 = w_vn[32 + o];
        const float wd0 = wd_vn[o], wd1 = wd_vn[16 + o], wd2 = wd_vn[32 + o];
        float pv[3], dv[3];
        float dot = 0.f, dsq = 0.f;
#pragma unroll
        for (int d = 0; d < 3; ++d) {
            const float pp = BN_SCALE * (L[0][d] * wv0 + L[1][d] * wv1 + L[2][d] * wv2);
            const float dd = L[0][d] * wd0 + L[1][d] * wd1 + L[2][d] * wd2;
            pv[d] = pp; dv[d] = dd;
            dot += pp * dd;
            dsq += dd * dd;
        }
        const float f = dot * __builtin_amdgcn_rcpf(dsq + VN_EPS);
        float acc = 0.f;
#pragma unroll
        for (int d = 0; d < 3; ++d) {
            const float corr = pv[d] - f * dv[d];
            const float sel  = (dot >= 0.f) ? pv[d] : corr;
            const float a    = NEG * pv[d] + POS * sel;
            acc += a * a;
        }
        sn[o] = __builtin_amdgcn_sqrtf(acc);
    }

    // ---- 16->8 conv + BN + relu: lane-local ------------------------------
    float tt[8];
#pragma unroll
    for (int op = 0; op < 4; ++op) {
        v2f t = {0.f, 0.f};
#pragma unroll
        for (int c = 0; c < 16; ++c)
            t += sn[c] * (*(const v2f*)&w_h1[c * 8 + 2 * op]);
        tt[2 * op + 0] = fmaxf(t[0] * BN_SCALE, 0.f);
        tt[2 * op + 1] = fmaxf(t[1] * BN_SCALE, 0.f);
    }

    // ---- 8->8 conv + bias, softmax over channels -------------------------
    float sc[8];
    float mx = -1e30f;
#pragma unroll
    for (int op = 0; op < 4; ++op) {
        v2f u = *(const v2f*)&b_h2[2 * op];
#pragma unroll
        for (int c = 0; c < 8; ++c)
            u += tt[c] * (*(const v2f*)&w_h2[c * 8 + 2 * op]);
        sc[2 * op + 0] = u[0];
        sc[2 * op + 1] = u[1];
        mx = fmaxf(mx, fmaxf(u[0], u[1]));
    }
    float se = 0.f;
#pragma unroll
    for (int o = 0; o < 8; ++o) { sc[o] = __expf(sc[o] - mx); se += sc[o]; }
    const float inv_se = __builtin_amdgcn_rcpf(se);
#pragma unroll
    for (int o = 0; o < 8; ++o) sc[o] *= inv_se;

    // ---- kernel-point correlation: PER-LANE fold over scores (sc is
    //      per-neighbor), project, normalize, mean over k ------------------
#pragma unroll
    for (int grp = 0; grp < 8; ++grp) {
        const int hb = grp * 4;
        v4f W0 = sc[0] * (*(const v4f*)&wb[0 * 256 + hb]);
        v4f W1 = sc[0] * (*(const v4f*)&wb[1 * 256 + hb]);
        v4f W2 = sc[0] * (*(const v4f*)&wb[2 * 256 + hb]);
#pragma unroll
        for (int s = 1; s < 8; ++s) {
            const float sv = sc[s];
            W0 += sv * (*(const v4f*)&wb[0 * 256 + s * 32 + hb]);
            W1 += sv * (*(const v4f*)&wb[1 * 256 + s * 32 + hb]);
            W2 += sv * (*(const v4f*)&wb[2 * 256 + s * 32 + hb]);
        }
        v4f V0 = L[0][0] * W0 + L[1][0] * W1 + L[2][0] * W2;
        v4f V1 = L[0][1] * W0 + L[1][1] * W1 + L[2][1] * W2;
        v4f V2 = L[0][2] * W0 + L[1][2] * W1 + L[2][2] * W2;
        v4f vv = V0 * V0 + V1 * V1 + V2 * V2;
        v4f inn;
#pragma unroll
        for (int e = 0; e < 4; ++e)
            inn[e] = __builtin_amdgcn_rsqf(fmaxf(vv[e], 1e-24f)) * 0.0625f; // 1/||v|| * (1/16)
        V0 *= inn; V1 *= inn; V2 *= inn;
        v4f X0, X1, X2;
#pragma unroll
        for (int e = 0; e < 4; ++e) {
            X0[e] = row16_sum15(V0[e]);
            X1[e] = row16_sum15(V1[e]);
            X2[e] = row16_sum15(V2[e]);
        }
        if (k == 15) {
            *(v4f*)&featsA[bp][0][hb] = X0;
            *(v4f*)&featsA[bp][1][hb] = X1;
            *(v4f*)&featsA[bp][2][hb] = X2;
        }
    }
    // intra-wave LDS write->read (in-order DS pipe + compiler lgkmcnt)

    // ---- VNLeakyReLU(32->32): lane owns o = {2k, 2k+1}; v2f weight loads,
    //      o stays vectorized -> no hsum -----------------------------------
    {
        v2f D0 = {0.f, 0.f}, D1 = D0, D2 = D0;
#pragma unroll
        for (int grp = 0; grp < 8; ++grp) {
            const int hb = grp * 4;
            const v4f f0 = *(const v4f*)&featsA[bp][0][hb];
            const v4f f1 = *(const v4f*)&featsA[bp][1][hb];
            const v4f f2 = *(const v4f*)&featsA[bp][2][hb];
#pragma unroll
            for (int e = 0; e < 4; ++e) {
                const v2f w = *(const v2f*)&wd_relu[(hb + e) * 32 + 2 * k];
                D0 += f0[e] * w;
                D1 += f1[e] * w;
                D2 += f2[e] * w;
            }
        }
        v2f R0, R1, R2;
#pragma unroll
        for (int j = 0; j < 2; ++j) {
            const int o = 2 * k + j;
            const float p0 = featsA[bp][0][o];
            const float p1 = featsA[bp][1][o];
            const float p2 = featsA[bp][2][o];
            const float d0 = D0[j], d1 = D1[j], d2 = D2[j];
            const float dot = p0 * d0 + p1 * d1 + p2 * d2;
            const float dsq = d0 * d0 + d1 * d1 + d2 * d2;
            const float f   = dot * __builtin_amdgcn_rcpf(dsq + VN_EPS);
            const bool  pos = (dot >= 0.f);
            R0[j] = NEG * p0 + POS * (pos ? p0 : (p0 - f * d0));
            R1[j] = NEG * p1 + POS * (pos ? p1 : (p1 - f * d1));
            R2[j] = NEG * p2 + POS * (pos ? p2 : (p2 - f * d2));
        }
        *(v2f*)&feats2A[bp][0][2 * k] = R0;
        *(v2f*)&feats2A[bp][1][2 * k] = R1;
        *(v2f*)&feats2A[bp][2][2 * k] = R2;
    }

    // ---- VNLinearLeakyReLU(32->64): lane owns o = 4k..4k+3; dwordx4
    //      weight loads, v4f accumulators over o, coalesced x4 stores ------
    {
        v4f AU0 = (v4f)0.f, AU1 = AU0, AU2 = AU0;
        v4f AV0 = AU0, AV1 = AU0, AV2 = AU0;
#pragma unroll
        for (int grp = 0; grp < 8; ++grp) {
            const int hb = grp * 4;
            const v4f f0 = *(const v4f*)&feats2A[bp][0][hb];
            const v4f f1 = *(const v4f*)&feats2A[bp][1][hb];
            const v4f f2 = *(const v4f*)&feats2A[bp][2][hb];
#pragma unroll
            for (int e = 0; e < 4; ++e) {
                const v4f wu = *(const v4f*)&w_un [(hb + e) * 64 + 4 * k];
                const v4f wd = *(const v4f*)&wd_un[(hb + e) * 64 + 4 * k];
                AU0 += f0[e] * wu; AU1 += f1[e] * wu; AU2 += f2[e] * wu;
                AV0 += f0[e] * wd; AV1 += f1[e] * wd; AV2 += f2[e] * wd;
            }
        }
        float O[12];
#pragma unroll
        for (int e = 0; e < 4; ++e) {
            const float u0 = AU0[e] * BN_SCALE;
            const float u1 = AU1[e] * BN_SCALE;
            const float u2 = AU2[e] * BN_SCALE;
            const float v0 = AV0[e], v1 = AV1[e], v2 = AV2[e];
            const float dot = u0 * v0 + u1 * v1 + u2 * v2;
            const float dsq = v0 * v0 + v1 * v1 + v2 * v2;
            const float f   = dot * __builtin_amdgcn_rcpf(dsq + VN_EPS);
            const bool  pos = (dot >= 0.f);
            O[3 * e + 0] = NEG * u0 + POS * (pos ? u0 : (u0 - f * v0));
            O[3 * e + 1] = NEG * u1 + POS * (pos ? u1 : (u1 - f * v1));
            O[3 * e + 2] = NEG * u2 + POS * (pos ? u2 : (u2 - f * v2));
        }
        // lane k covers out[n, 4k..4k+4, :] = 12 contiguous floats; a row of
        // 16 lanes covers the point's whole 192-float slab contiguously.
        float* dst = out + (long)n * 192 + 12 * k;
        *(v4f*)(dst + 0) = *(const v4f*)&O[0];
        *(v4f*)(dst + 4) = *(const v4f*)&O[4];
        *(v4f*)(dst + 8) = *(const v4f*)&O[8];
    }
}

extern "C" void kernel_launch(void* const* d_in, const int* in_sizes, int n_in,
                              void* d_out, int out_size, void* d_ws, size_t ws_size,
                              hipStream_t stream) {
    const float* q_pts   = (const float*)d_in[0];
    const float* s_pts   = (const float*)d_in[1];
    // d_in[2] = s_feats: unused by the reference
    const int*   nbr     = (const int*)  d_in[3];
    const float* wb      = (const float*)d_in[4];
    const float* w_vn    = (const float*)d_in[5];
    const float* wd_vn   = (const float*)d_in[6];
    const float* w_h1    = (const float*)d_in[7];
    const float* w_h2    = (const float*)d_in[8];
    const float* b_h2    = (const float*)d_in[9];
    const float* wd_relu = (const float*)d_in[10];
    const float* w_un    = (const float*)d_in[11];
    const float* wd_un   = (const float*)d_in[12];
    float* out = (float*)d_out;

    const int N = in_sizes[0] / 3;          // q_pts is [N,3]
    const int blocks = (N + 7) / 8;         // 8 points/block, 4 per wave, 2 waves
    areconv_kernel<<<blocks, 128, 0, stream>>>(
        q_pts, s_pts, nbr, wb, w_vn, wd_vn, w_h1, w_h2, b_h2,
        wd_relu, w_un, wd_un, out, N);
}

// Round 10
// 107.741 us; speedup vs baseline: 1.3976x; 1.0028x over previous
//
#include <hip/hip_runtime.h>
#include <math.h>

#define VN_EPS   1e-6f
#define NEG      0.2f
#define POS      0.8f   // 1 - NEG

typedef float v2f __attribute__((ext_vector_type(2)));
typedef float v4f __attribute__((ext_vector_type(4)));

// ---- DPP 16-lane (row) reductions: VALU-only, HW-verified R3-R8 ------------
template <int CTRL>
__device__ __forceinline__ float dpp_add(float v) {
    int s = __builtin_amdgcn_update_dpp(0, __float_as_int(v), CTRL, 0xf, 0xf, true);
    return v + __int_as_float(s);
}
__device__ __forceinline__ float row16_allsum(float v) {
    v = dpp_add<0x128>(v);  // row_ror:8
    v = dpp_add<0x124>(v);  // row_ror:4
    v = dpp_add<0x122>(v);  // row_ror:2
    v = dpp_add<0x121>(v);  // row_ror:1
    return v;
}
__device__ __forceinline__ float row16_sum15(float v) {
    v = dpp_add<0x118>(v);  // row_shr:8
    v = dpp_add<0x114>(v);  // row_shr:4
    v = dpp_add<0x112>(v);  // row_shr:2
    v = dpp_add<0x111>(v);  // row_shr:1
    return v;
}

// 4 points per wave (lane = p*16 + k); 2 waves/block, 8 points/block, 2000 WGs.
// R10: kernel time was pinned at ~41us across R5-R8 geometries/instruction
// mixes with ~87% per-wave stall unexplained by VMEM/LDS — hypothesis:
// I-cache thrash (fully-unrolled body ~40KB >> 32KB I$). This version ROLLS
// the four big loops (#pragma unroll 1) to shrink static code to ~7KB.
// NOTE (R6): scores sc[] are PER-NEIGHBOR — never dedup the fold across k.
// NOTE (R9): bf16 fold before normalize fails (1/||V|| amplifies quantization);
// the fold must stay fp32 (or split-bf16) — keep fp32 here.
__global__ __launch_bounds__(128) void areconv_kernel(
    const float* __restrict__ q_pts,    // [N,3]
    const float* __restrict__ s_pts,    // [N2,3]
    const int*   __restrict__ nbr,      // [N,16]
    const float* __restrict__ wb,       // [3,256]
    const float* __restrict__ w_vn,     // [3,16]
    const float* __restrict__ wd_vn,    // [3,16]
    const float* __restrict__ w_h1,     // [16,8]
    const float* __restrict__ w_h2,     // [8,8]
    const float* __restrict__ b_h2,     // [8]
    const float* __restrict__ wd_relu,  // [32,32]
    const float* __restrict__ w_un,     // [32,64]
    const float* __restrict__ wd_un,    // [32,64]
    float* __restrict__ out,            // [N,64,3]
    int N)
{
    const float BN_SCALE = 0.999994993f;  // float32(1/sqrt(1+1e-5))

    // per-point staging, d-major [bp][d][h], stride 36 (144 B, v4f-aligned).
    // All traffic intra-wave -> in-order DS pipe + compiler lgkmcnt, no
    // barriers (pattern HW-validated R4-R8).
    __shared__ __align__(16) float featsA [8][3][36];
    __shared__ __align__(16) float feats2A[8][3][36];

    const int tid  = threadIdx.x;
    const int wv   = tid >> 6;        // 0..1
    const int lane = tid & 63;
    const int p    = lane >> 4;       // DPP row = point-in-wave
    const int k    = lane & 15;       // neighbor index
    const int bp   = wv * 4 + p;      // point slot in block (0..7)
    int n = blockIdx.x * 8 + bp;
    n = (n < N) ? n : (N - 1);        // N=16000 -> never clamps

    // ---- gather + center + cross -> local frame L[c][d] ------------------
    const float qx = q_pts[n * 3 + 0];
    const float qy = q_pts[n * 3 + 1];
    const float qz = q_pts[n * 3 + 2];
    const int   id = nbr[n * 16 + k];
    const float px = s_pts[id * 3 + 0] - qx;
    const float py = s_pts[id * 3 + 1] - qy;
    const float pz = s_pts[id * 3 + 2] - qz;

    const float cx = row16_allsum(px) * 0.0625f;
    const float cy = row16_allsum(py) * 0.0625f;
    const float cz = row16_allsum(pz) * 0.0625f;

    const float rx = py * cz - pz * cy;
    const float ry = pz * cx - px * cz;
    const float rz = px * cy - py * cx;

    const float L[3][3] = {{px, py, pz}, {cx, cy, cz}, {rx, ry, rz}};

    // ---- score net VNLinearLeakyReLU(3->16)->||.|| FUSED with the 16->8
    //      conv, ROLLED over o (16 iters) so sn[] never needs an array -----
    v2f t01 = {0.f, 0.f}, t23 = t01, t45 = t01, t67 = t01;
#pragma unroll 1
    for (int o = 0; o < 16; ++o) {
        const float wv0 = w_vn[o],  wv1 = w_vn[16 + o],  wv2 = w_vn[32 + o];
        const float wd0 = wd_vn[o], wd1 = wd_vn[16 + o], wd2 = wd_vn[32 + o];
        float pv[3], dv[3];
        float dot = 0.f, dsq = 0.f;
#pragma unroll
        for (int d = 0; d < 3; ++d) {
            const float pp = BN_SCALE * (L[0][d] * wv0 + L[1][d] * wv1 + L[2][d] * wv2);
            const float dd = L[0][d] * wd0 + L[1][d] * wd1 + L[2][d] * wd2;
            pv[d] = pp; dv[d] = dd;
            dot += pp * dd;
            dsq += dd * dd;
        }
        const float f = dot * __builtin_amdgcn_rcpf(dsq + VN_EPS);
        float acc = 0.f;
#pragma unroll
        for (int d = 0; d < 3; ++d) {
            const float corr = pv[d] - f * dv[d];
            const float sel  = (dot >= 0.f) ? pv[d] : corr;
            const float a    = NEG * pv[d] + POS * sel;
            acc += a * a;
        }
        const float s = __builtin_amdgcn_sqrtf(acc);
        t01 += s * (*(const v2f*)&w_h1[o * 8 + 0]);
        t23 += s * (*(const v2f*)&w_h1[o * 8 + 2]);
        t45 += s * (*(const v2f*)&w_h1[o * 8 + 4]);
        t67 += s * (*(const v2f*)&w_h1[o * 8 + 6]);
    }
    float tt[8];
    tt[0] = fmaxf(t01[0] * BN_SCALE, 0.f);  tt[1] = fmaxf(t01[1] * BN_SCALE, 0.f);
    tt[2] = fmaxf(t23[0] * BN_SCALE, 0.f);  tt[3] = fmaxf(t23[1] * BN_SCALE, 0.f);
    tt[4] = fmaxf(t45[0] * BN_SCALE, 0.f);  tt[5] = fmaxf(t45[1] * BN_SCALE, 0.f);
    tt[6] = fmaxf(t67[0] * BN_SCALE, 0.f);  tt[7] = fmaxf(t67[1] * BN_SCALE, 0.f);

    // ---- 8->8 conv + bias, softmax (small; stays unrolled so sc[] is
    //      register-indexed) ----------------------------------------------
    float sc[8];
    float mx = -1e30f;
#pragma unroll
    for (int op = 0; op < 4; ++op) {
        v2f u = *(const v2f*)&b_h2[2 * op];
#pragma unroll
        for (int c = 0; c < 8; ++c)
            u += tt[c] * (*(const v2f*)&w_h2[c * 8 + 2 * op]);
        sc[2 * op + 0] = u[0];
        sc[2 * op + 1] = u[1];
        mx = fmaxf(mx, fmaxf(u[0], u[1]));
    }
    float se = 0.f;
#pragma unroll
    for (int o = 0; o < 8; ++o) { sc[o] = __expf(sc[o] - mx); se += sc[o]; }
    const float inv_se = __builtin_amdgcn_rcpf(se);
#pragma unroll
    for (int o = 0; o < 8; ++o) sc[o] *= inv_se;

    // ---- kernel-point correlation: per-lane fp32 fold (sc is per-neighbor),
    //      project, normalize, mean over k. ROLLED over h-groups -----------
#pragma unroll 1
    for (int grp = 0; grp < 8; ++grp) {
        const int hb = grp * 4;
        v4f W0 = sc[0] * (*(const v4f*)&wb[0 * 256 + hb]);
        v4f W1 = sc[0] * (*(const v4f*)&wb[1 * 256 + hb]);
        v4f W2 = sc[0] * (*(const v4f*)&wb[2 * 256 + hb]);
#pragma unroll
        for (int s = 1; s < 8; ++s) {
            const float sv = sc[s];
            W0 += sv * (*(const v4f*)&wb[0 * 256 + s * 32 + hb]);
            W1 += sv * (*(const v4f*)&wb[1 * 256 + s * 32 + hb]);
            W2 += sv * (*(const v4f*)&wb[2 * 256 + s * 32 + hb]);
        }
        v4f V0 = L[0][0] * W0 + L[1][0] * W1 + L[2][0] * W2;
        v4f V1 = L[0][1] * W0 + L[1][1] * W1 + L[2][1] * W2;
        v4f V2 = L[0][2] * W0 + L[1][2] * W1 + L[2][2] * W2;
        v4f vv = V0 * V0 + V1 * V1 + V2 * V2;
        v4f inn;
#pragma unroll
        for (int e = 0; e < 4; ++e)
            inn[e] = __builtin_amdgcn_rsqf(fmaxf(vv[e], 1e-24f)) * 0.0625f; // 1/||v|| * (1/16)
        V0 *= inn; V1 *= inn; V2 *= inn;
        v4f X0, X1, X2;
#pragma unroll
        for (int e = 0; e < 4; ++e) {
            X0[e] = row16_sum15(V0[e]);
            X1[e] = row16_sum15(V1[e]);
            X2[e] = row16_sum15(V2[e]);
        }
        if (k == 15) {
            *(v4f*)&featsA[bp][0][hb] = X0;
            *(v4f*)&featsA[bp][1][hb] = X1;
            *(v4f*)&featsA[bp][2][hb] = X2;
        }
    }
    // intra-wave LDS write->read (in-order DS pipe + compiler lgkmcnt)

    // ---- VNLeakyReLU(32->32): lane owns o = {2k, 2k+1}; ROLLED over h ----
    {
        v2f D0 = {0.f, 0.f}, D1 = D0, D2 = D0;
#pragma unroll 1
        for (int grp = 0; grp < 8; ++grp) {
            const int hb = grp * 4;
            const v4f f0 = *(const v4f*)&featsA[bp][0][hb];
            const v4f f1 = *(const v4f*)&featsA[bp][1][hb];
            const v4f f2 = *(const v4f*)&featsA[bp][2][hb];
#pragma unroll
            for (int e = 0; e < 4; ++e) {
                const v2f w = *(const v2f*)&wd_relu[(hb + e) * 32 + 2 * k];
                D0 += f0[e] * w;
                D1 += f1[e] * w;
                D2 += f2[e] * w;
            }
        }
        v2f R0, R1, R2;
#pragma unroll
        for (int j = 0; j < 2; ++j) {
            const int o = 2 * k + j;
            const float p0 = featsA[bp][0][o];
            const float p1 = featsA[bp][1][o];
            const float p2 = featsA[bp][2][o];
            const float d0 = D0[j], d1 = D1[j], d2 = D2[j];
            const float dot = p0 * d0 + p1 * d1 + p2 * d2;
            const float dsq = d0 * d0 + d1 * d1 + d2 * d2;
            const float f   = dot * __builtin_amdgcn_rcpf(dsq + VN_EPS);
            const bool  pos = (dot >= 0.f);
            R0[j] = NEG * p0 + POS * (pos ? p0 : (p0 - f * d0));
            R1[j] = NEG * p1 + POS * (pos ? p1 : (p1 - f * d1));
            R2[j] = NEG * p2 + POS * (pos ? p2 : (p2 - f * d2));
        }
        *(v2f*)&feats2A[bp][0][2 * k] = R0;
        *(v2f*)&feats2A[bp][1][2 * k] = R1;
        *(v2f*)&feats2A[bp][2][2 * k] = R2;
    }

    // ---- VNLinearLeakyReLU(32->64): lane owns o = 4k..4k+3; ROLLED -------
    {
        v4f AU0 = (v4f)0.f, AU1 = AU0, AU2 = AU0;
        v4f AV0 = AU0, AV1 = AU0, AV2 = AU0;
#pragma unroll 1
        for (int grp = 0; grp < 8; ++grp) {
            const int hb = grp * 4;
            const v4f f0 = *(const v4f*)&feats2A[bp][0][hb];
            const v4f f1 = *(const v4f*)&feats2A[bp][1][hb];
            const v4f f2 = *(const v4f*)&feats2A[bp][2][hb];
#pragma unroll
            for (int e = 0; e < 4; ++e) {
                const v4f wu = *(const v4f*)&w_un [(hb + e) * 64 + 4 * k];
                const v4f wd = *(const v4f*)&wd_un[(hb + e) * 64 + 4 * k];
                AU0 += f0[e] * wu; AU1 += f1[e] * wu; AU2 += f2[e] * wu;
                AV0 += f0[e] * wd; AV1 += f1[e] * wd; AV2 += f2[e] * wd;
            }
        }
        float O[12];
#pragma unroll
        for (int e = 0; e < 4; ++e) {
            const float u0 = AU0[e] * BN_SCALE;
            const float u1 = AU1[e] * BN_SCALE;
            const float u2 = AU2[e] * BN_SCALE;
            const float v0 = AV0[e], v1 = AV1[e], v2 = AV2[e];
            const float dot = u0 * v0 + u1 * v1 + u2 * v2;
            const float dsq = v0 * v0 + v1 * v1 + v2 * v2;
            const float f   = dot * __builtin_amdgcn_rcpf(dsq + VN_EPS);
            const bool  pos = (dot >= 0.f);
            O[3 * e + 0] = NEG * u0 + POS * (pos ? u0 : (u0 - f * v0));
            O[3 * e + 1] = NEG * u1 + POS * (pos ? u1 : (u1 - f * v1));
            O[3 * e + 2] = NEG * u2 + POS * (pos ? u2 : (u2 - f * v2));
        }
        // lane k covers out[n, 4k..4k+4, :] = 12 contiguous floats; 16 lanes
        // cover the point's whole 192-float slab contiguously.
        float* dst = out + (long)n * 192 + 12 * k;
        *(v4f*)(dst + 0) = *(const v4f*)&O[0];
        *(v4f*)(dst + 4) = *(const v4f*)&O[4];
        *(v4f*)(dst + 8) = *(const v4f*)&O[8];
    }
}

extern "C" void kernel_launch(void* const* d_in, const int* in_sizes, int n_in,
                              void* d_out, int out_size, void* d_ws, size_t ws_size,
                              hipStream_t stream) {
    const float* q_pts   = (const float*)d_in[0];
    const float* s_pts   = (const float*)d_in[1];
    // d_in[2] = s_feats: unused by the reference
    const int*   nbr     = (const int*)  d_in[3];
    const float* wb      = (const float*)d_in[4];
    const float* w_vn    = (const float*)d_in[5];
    const float* wd_vn   = (const float*)d_in[6];
    const float* w_h1    = (const float*)d_in[7];
    const float* w_h2    = (const float*)d_in[8];
    const float* b_h2    = (const float*)d_in[9];
    const float* wd_relu = (const float*)d_in[10];
    const float* w_un    = (const float*)d_in[11];
    const float* wd_un   = (const float*)d_in[12];
    float* out = (float*)d_out;

    const int N = in_sizes[0] / 3;          // q_pts is [N,3]
    const int blocks = (N + 7) / 8;         // 8 points/block, 4 per wave
    areconv_kernel<<<blocks, 128, 0, stream>>>(
        q_pts, s_pts, nbr, wb, w_vn, wd_vn, w_h1, w_h2, b_h2,
        wd_relu, w_un, wd_un, out, N);
}